// Round 12
// baseline (157.969 us; speedup 1.0000x reference)
//
#include <hip/hip_runtime.h>

#define SEG 24
#define DD  32
#define HEPS 1e-7f
#define N_ITERS 10

typedef _Float16 h2 __attribute__((ext_vector_type(2)));
typedef __fp16   f16v2 __attribute__((ext_vector_type(2)));

__device__ __forceinline__ float frcp(float x) { return __builtin_amdgcn_rcpf(x); }

__device__ __forceinline__ float qx1(float x) {
    return __int_as_float(__builtin_amdgcn_mov_dpp(__float_as_int(x), 0xB1, 0xF, 0xF, true));
}
__device__ __forceinline__ float qx2(float x) {
    return __int_as_float(__builtin_amdgcn_mov_dpp(__float_as_int(x), 0x4E, 0xF, 0xF, true));
}
__device__ __forceinline__ float qsum(float x) {
    x += qx1(x);
    x += qx2(x);
    return x;
}

__device__ __forceinline__ float acosh_coef(float a) {
    float am = fmaf(a, a, -1.0f);
    float s  = sqrtf(am);
    return __logf(a + s) * frcp(s);
}

__device__ __forceinline__ float edot8(const float a[8], const float b[8]) {
    float x = fmaf(a[0], b[0], a[1] * b[1]);
    float y = fmaf(a[2], b[2], a[3] * b[3]);
    float z = fmaf(a[4], b[4], a[5] * b[5]);
    float w = fmaf(a[6], b[6], a[7] * b[7]);
    return qsum((x + y) + (z + w));
}

__device__ __forceinline__ unsigned pk_u32(float a, float b) {
    union { f16v2 f; unsigned u; } c;
    c.f = __builtin_amdgcn_cvt_pkrtz(a, b);
    return c.u;
}
__device__ __forceinline__ h2 pk_h2(float a, float b) {
    union { f16v2 f; h2 h; } c;
    c.f = __builtin_amdgcn_cvt_pkrtz(a, b);
    return c.h;
}
__device__ __forceinline__ h2 as_h2(unsigned u) {
    union { unsigned u; h2 h; } c; c.u = u; return c.h;
}

// ws layout (dwords): [0,1536) packed W f16x2 (s*384 + row*12 + j)
//                     [1536,1664) b f32 (s*32 + d) ; [1664] tanh(es)
#define WS_B_OFF 1536
#define WS_TS_OFF 1664

// ============ K0: pack W to f16x2, copy b, tanh(es) -> d_ws =================
__global__ __launch_bounds__(256)
void prep_kernel(const float* __restrict__ W0, const float* __restrict__ b0,
                 const float* __restrict__ W1, const float* __restrict__ b1,
                 const float* __restrict__ W2, const float* __restrict__ b2,
                 const float* __restrict__ W3, const float* __restrict__ b3,
                 const float* __restrict__ es, unsigned* __restrict__ ws)
{
    const int t = blockIdx.x * blockDim.x + threadIdx.x;
    const float* Ws[4] = { W0, W1, W2, W3 };
    const float* bs[4] = { b0, b1, b2, b3 };
    if (t < 1536) {
        int s = t / 384, rem = t % 384, r = rem / 12, j = rem % 12;
        float a = Ws[s][r * SEG + 2 * j];
        float b = Ws[s][r * SEG + 2 * j + 1];
        ws[t] = pk_u32(a, b);
    } else if (t < 1664) {
        int p = t - 1536;
        reinterpret_cast<float*>(ws)[WS_B_OFF + p] = bs[p / 32][p % 32];
    } else if (t == 1664) {
        reinterpret_cast<float*>(ws)[WS_TS_OFF] = tanhf(es[0]);
    }
}

// ============ K1: encode; LDS-staged x reads AND h stores ===================
__global__ __launch_bounds__(256)
void encode_kernel(const float* __restrict__ x0, const float* __restrict__ x1,
                   const float* __restrict__ x2, const float* __restrict__ x3,
                   const unsigned* __restrict__ ws,
                   float* __restrict__ out, int n_items)
{
    __shared__ float lds[256 * DD];                 // 32 KB, reused x-stage / h-stage

    const int tid   = threadIdx.x;
    const int item0 = blockIdx.x * 256;
    const int item  = item0 + tid;
    const int s     = blockIdx.y;                   // wave-uniform stream id

    const float* xp;
    if      (s == 0) xp = x0;
    else if (s == 1) xp = x1;
    else if (s == 2) xp = x2;
    else             xp = x3;

    const unsigned* W2p = ws + (size_t)s * 384;     // s_load source
    const float*    B2p = reinterpret_cast<const float*>(ws) + WS_B_OFF + s * 32;
    const float     ts  = reinterpret_cast<const float*>(ws)[WS_TS_OFF];

    // ---- phase A: cooperative dense x load -> LDS rows padded 24->25 ------
    {
        const float* xbase = xp + (size_t)item0 * SEG;
        const int nvalid = min(256, n_items - item0);      // full blocks: 256
        #pragma unroll
        for (int c = 0; c < SEG; ++c) {
            int f   = c * 256 + tid;                       // 0..6143
            int it  = f / SEG;
            int off = f - it * SEG;
            if (it < nvalid) lds[it * 25 + off] = xbase[f];
        }
    }
    __syncthreads();

    bool active = (item < n_items);
    float u[DD];

    if (active) {
        // ---- phase B: seg from LDS (stride 25 -> conflict-free) -----------
        float seg[SEG];
        #pragma unroll
        for (int k = 0; k < SEG; ++k) seg[k] = lds[tid * 25 + k];

        h2 sp2[SEG / 2];
        #pragma unroll
        for (int j = 0; j < SEG / 2; ++j)
            sp2[j] = pk_h2(seg[2*j], seg[2*j+1]);

        #pragma unroll
        for (int d = 0; d < DD; ++d) {
            float z = B2p[d];                        // wave-uniform -> s_load
            #pragma unroll
            for (int j = 0; j < SEG / 2; ++j)
                z = __builtin_amdgcn_fdot2(sp2[j], as_h2(W2p[d * 12 + j]), z, false);
            u[d] = z * ts;
        }

        // <u,u>_L = sum(u^2) - 2*u0^2, 4-way partials
        float q0 = 0.f, q1 = 0.f, q2 = 0.f, q3 = 0.f;
        #pragma unroll
        for (int d = 0; d < DD; d += 4) {
            q0 = fmaf(u[d+0], u[d+0], q0);
            q1 = fmaf(u[d+1], u[d+1], q1);
            q2 = fmaf(u[d+2], u[d+2], q2);
            q3 = fmaf(u[d+3], u[d+3], q3);
        }
        float sq = (q0 + q1) + (q2 + q3) - 2.0f * u[0] * u[0];
        sq = fmaxf(sq, 1e-12f);
        float nrm = sqrtf(sq);
        float ep = __expf(nrm), em = frcp(ep);
        float sh = 0.5f * (ep - em);
        float sc = sh * frcp(fmaxf(nrm, HEPS));

        float r0 = 0.f, r1 = 0.f, r2 = 0.f, r3 = 0.f;
        #pragma unroll
        for (int d = 1; d < DD; ++d) {
            float yv = sc * u[d];
            u[d] = yv;
            if ((d & 3) == 0) r0 = fmaf(yv, yv, r0);
            else if ((d & 3) == 1) r1 = fmaf(yv, yv, r1);
            else if ((d & 3) == 2) r2 = fmaf(yv, yv, r2);
            else r3 = fmaf(yv, yv, r3);
        }
        u[0] = sqrtf(1.0f + (r0 + r1) + (r2 + r3));  // projx time component
    }

    __syncthreads();   // all x reads done; LDS now reused for h staging

    if (active) {
        // swizzled LDS write: float4 slot q = tid*8 + (j ^ (tid&7))
        #pragma unroll
        for (int j = 0; j < DD / 4; ++j) {
            int q = tid * 8 + (j ^ (tid & 7));
            reinterpret_cast<float4*>(lds)[q] =
                make_float4(u[4*j+0], u[4*j+1], u[4*j+2], u[4*j+3]);
        }
    }

    __syncthreads();

    // cooperative dense store: 2048 float4 contiguous
    float4* obase = reinterpret_cast<float4*>(
        out + (size_t)s * ((size_t)n_items * DD) + (size_t)item0 * DD);
    #pragma unroll
    for (int c = 0; c < 8; ++c) {
        int f4   = c * 256 + tid;
        int it_r = f4 >> 3;
        int j    = tid & 7;
        if (item0 + it_r < n_items) {
            int q = it_r * 8 + (j ^ (it_r & 7));
            obase[f4] = reinterpret_cast<const float4*>(lds)[q];
        }
    }
}

// ============ K2: fusion, 4 lanes per item; h in registers, single read =====
#define GMV(o0,o1,o2,o3,o4, v0,v1,v2,v3,v4)                                   \
    o0 = fmaf(G00,(v0), fmaf(G01,(v1), fmaf(G02,(v2), fmaf(G03,(v3), nt0*(v4))))); \
    o1 = fmaf(G01,(v0), fmaf(G11,(v1), fmaf(G12,(v2), fmaf(G13,(v3), nt1*(v4))))); \
    o2 = fmaf(G02,(v0), fmaf(G12,(v1), fmaf(G22,(v2), fmaf(G23,(v3), nt2*(v4))))); \
    o3 = fmaf(G03,(v0), fmaf(G13,(v1), fmaf(G23,(v2), fmaf(G33,(v3), nt3*(v4))))); \
    o4 = fmaf(nt0,(v0), fmaf(nt1,(v1), fmaf(nt2,(v2), fmaf(nt3,(v3), -(v4)))));

#define DOT5(a0,a1,a2,a3,a4, c0,c1,c2,c3,c4) \
    fmaf((a0),(c0), fmaf((a1),(c1), fmaf((a2),(c2), fmaf((a3),(c3), (a4)*(c4)))))

__global__ __launch_bounds__(256)
void fusion_kernel(const float* __restrict__ lw,
                   float* __restrict__ out, int n_items)
{
    const int T    = blockIdx.x * blockDim.x + threadIdx.x;
    const int item = T >> 2;
    const int sub  = T & 3;
    if (item >= n_items) return;

    float l0 = lw[0], l1 = lw[1], l2 = lw[2], l3 = lw[3];
    float mxw = fmaxf(fmaxf(l0, l1), fmaxf(l2, l3));
    float e0 = __expf(l0 - mxw), e1 = __expf(l1 - mxw),
          e2 = __expf(l2 - mxw), e3 = __expf(l3 - mxw);
    float winv = frcp(e0 + e1 + e2 + e3);
    float w0 = e0 * winv, w1 = e1 * winv, w2 = e2 * winv, w3 = e3 * winv;

    const size_t osz = (size_t)n_items * DD;

    float hv[4][8];
    #pragma unroll
    for (int s = 0; s < 4; ++s) {
        const float4* p = reinterpret_cast<const float4*>(
            out + (size_t)s * osz + (size_t)item * DD + sub * 8);
        float4 a = p[0], b = p[1];
        hv[s][0] = a.x; hv[s][1] = a.y; hv[s][2] = a.z; hv[s][3] = a.w;
        hv[s][4] = b.x; hv[s][5] = b.y; hv[s][6] = b.z; hv[s][7] = b.w;
    }

    const float is0 = (sub == 0) ? 1.0f : 0.0f;
    float tau0 = qsum(is0 * hv[0][0]);
    float tau1 = qsum(is0 * hv[1][0]);
    float tau2 = qsum(is0 * hv[2][0]);
    float tau3 = qsum(is0 * hv[3][0]);

    float d00 = edot8(hv[0], hv[0]);
    float d01 = edot8(hv[0], hv[1]);
    float d02 = edot8(hv[0], hv[2]);
    float d03 = edot8(hv[0], hv[3]);
    float d11 = edot8(hv[1], hv[1]);
    float d12 = edot8(hv[1], hv[2]);
    float d13 = edot8(hv[1], hv[3]);
    float d22 = edot8(hv[2], hv[2]);
    float d23 = edot8(hv[2], hv[3]);
    float d33 = edot8(hv[3], hv[3]);

    float G00 = fmaf(-2.0f*tau0, tau0, d00);
    float G01 = fmaf(-2.0f*tau0, tau1, d01);
    float G02 = fmaf(-2.0f*tau0, tau2, d02);
    float G03 = fmaf(-2.0f*tau0, tau3, d03);
    float G11 = fmaf(-2.0f*tau1, tau1, d11);
    float G12 = fmaf(-2.0f*tau1, tau2, d12);
    float G13 = fmaf(-2.0f*tau1, tau3, d13);
    float G22 = fmaf(-2.0f*tau2, tau2, d22);
    float G23 = fmaf(-2.0f*tau2, tau3, d23);
    float G33 = fmaf(-2.0f*tau3, tau3, d33);
    float nt0 = -tau0, nt1 = -tau1, nt2 = -tau2, nt3 = -tau3;

    float b0v, b1v, b2v, b3v, b4v, g0, g1, g2, g3, g4;
    {
        float al0 = fmaxf(tau0, 1.0f + HEPS);
        float al1 = fmaxf(tau1, 1.0f + HEPS);
        float al2 = fmaxf(tau2, 1.0f + HEPS);
        float al3 = fmaxf(tau3, 1.0f + HEPS);
        float cc0 = w0 * acosh_coef(al0);
        float cc1 = w1 * acosh_coef(al1);
        float cc2 = w2 * acosh_coef(al2);
        float cc3 = w3 * acosh_coef(al3);
        b0v = cc0; b1v = cc1; b2v = cc2; b3v = cc3;
        b4v = -DOT5(cc0, cc1, cc2, cc3, 0.0f, al0, al1, al2, al3, 0.0f);

        GMV(g0, g1, g2, g3, g4, b0v, b1v, b2v, b3v, b4v);
        float gq = DOT5(g0, g1, g2, g3, g4, b0v, b1v, b2v, b3v, b4v);
        float sq = fmaxf(gq, 1e-12f);
        float nrm = sqrtf(sq);
        float ep = __expf(nrm), em = frcp(ep);
        float ch = 0.5f * (ep + em);
        float sc = 0.5f * (ep - em) * frcp(fmaxf(nrm, HEPS));
        b0v *= sc; b1v *= sc; b2v *= sc; b3v *= sc;
        b4v = fmaf(sc, b4v, ch);

        GMV(g0, g1, g2, g3, g4, b0v, b1v, b2v, b3v, b4v);
        float xx = DOT5(g0, g1, g2, g3, g4, b0v, b1v, b2v, b3v, b4v);
        float xt = DOT5(b0v, b1v, b2v, b3v, b4v, tau0, tau1, tau2, tau3, 1.0f);
        float tc = sqrtf(fmaf(xt, xt, 1.0f + xx));
        float dl = tc - xt;
        b4v += dl;
        g0 = fmaf(dl, nt0, g0); g1 = fmaf(dl, nt1, g1);
        g2 = fmaf(dl, nt2, g2); g3 = fmaf(dl, nt3, g3);
        g4 -= dl;
    }

    for (int it = 0; it < N_ITERS; ++it) {
        float al0 = fmaxf(-g0, 1.0f + HEPS);
        float al1 = fmaxf(-g1, 1.0f + HEPS);
        float al2 = fmaxf(-g2, 1.0f + HEPS);
        float al3 = fmaxf(-g3, 1.0f + HEPS);
        float cc0 = w0 * acosh_coef(al0);
        float cc1 = w1 * acosh_coef(al1);
        float cc2 = w2 * acosh_coef(al2);
        float cc3 = w3 * acosh_coef(al3);
        float S = DOT5(cc0, cc1, cc2, cc3, 0.0f, al0, al1, al2, al3, 0.0f);

        float gm0 = fmaf(-S, b0v, cc0);
        float gm1 = fmaf(-S, b1v, cc1);
        float gm2 = fmaf(-S, b2v, cc2);
        float gm3 = fmaf(-S, b3v, cc3);
        float gm4 = -S * b4v;

        float Gg0, Gg1, Gg2, Gg3, Gg4;
        GMV(Gg0, Gg1, Gg2, Gg3, Gg4, gm0, gm1, gm2, gm3, gm4);
        float qq = DOT5(Gg0, Gg1, Gg2, Gg3, Gg4, gm0, gm1, gm2, gm3, gm4);

        float sq = fmaxf(0.25f * qq, 1e-12f);
        float nrm = sqrtf(sq);
        float ep = __expf(nrm), em = frcp(ep);
        float ch = 0.5f * (ep + em);
        float sc = 0.25f * (ep - em) * frcp(fmaxf(nrm, HEPS));

        b0v = fmaf(ch, b0v, sc * gm0);
        b1v = fmaf(ch, b1v, sc * gm1);
        b2v = fmaf(ch, b2v, sc * gm2);
        b3v = fmaf(ch, b3v, sc * gm3);
        b4v = fmaf(ch, b4v, sc * gm4);
        g0  = fmaf(ch, g0, sc * Gg0);
        g1  = fmaf(ch, g1, sc * Gg1);
        g2  = fmaf(ch, g2, sc * Gg2);
        g3  = fmaf(ch, g3, sc * Gg3);
        g4  = fmaf(ch, g4, sc * Gg4);

        float xx = DOT5(g0, g1, g2, g3, g4, b0v, b1v, b2v, b3v, b4v);
        float xt = DOT5(b0v, b1v, b2v, b3v, b4v, tau0, tau1, tau2, tau3, 1.0f);
        float tc = sqrtf(fmaf(xt, xt, 1.0f + xx));
        float dl = tc - xt;
        b4v += dl;
        g0 = fmaf(dl, nt0, g0); g1 = fmaf(dl, nt1, g1);
        g2 = fmaf(dl, nt2, g2); g3 = fmaf(dl, nt3, g3);
        g4 -= dl;
    }

    float r[8];
    #pragma unroll
    for (int j = 0; j < 8; ++j)
        r[j] = fmaf(b0v, hv[0][j], fmaf(b1v, hv[1][j],
               fmaf(b2v, hv[2][j], b3v * hv[3][j])));
    if (sub == 0) r[0] += b4v;

    float4* po = reinterpret_cast<float4*>(
        out + (size_t)4 * osz + (size_t)item * DD + sub * 8);
    po[0] = make_float4(r[0], r[1], r[2], r[3]);
    po[1] = make_float4(r[4], r[5], r[6], r[7]);
}

extern "C" void kernel_launch(void* const* d_in, const int* in_sizes, int n_in,
                              void* d_out, int out_size, void* d_ws, size_t ws_size,
                              hipStream_t stream)
{
    const float* x0 = (const float*)d_in[0];
    const float* x1 = (const float*)d_in[1];
    const float* x2 = (const float*)d_in[2];
    const float* x3 = (const float*)d_in[3];
    const float* W0 = (const float*)d_in[4];
    const float* b0 = (const float*)d_in[5];
    const float* W1 = (const float*)d_in[6];
    const float* b1 = (const float*)d_in[7];
    const float* W2 = (const float*)d_in[8];
    const float* b2 = (const float*)d_in[9];
    const float* W3 = (const float*)d_in[10];
    const float* b3 = (const float*)d_in[11];
    const float* es = (const float*)d_in[12];
    const float* lw = (const float*)d_in[13];

    const int n_items = in_sizes[0] / SEG;   // 262144
    const int block = 256;

    prep_kernel<<<7, block, 0, stream>>>(W0, b0, W1, b1, W2, b2, W3, b3,
                                         es, (unsigned*)d_ws);

    const int gx = (n_items + block - 1) / block;
    dim3 grid1(gx, 4, 1);
    encode_kernel<<<grid1, block, 0, stream>>>(x0, x1, x2, x3,
                                               (const unsigned*)d_ws,
                                               (float*)d_out, n_items);

    const int n_threads = n_items * 4;
    const int gx2 = (n_threads + block - 1) / block;
    fusion_kernel<<<gx2, block, 0, stream>>>(lw, (float*)d_out, n_items);
}

// Round 13
// 147.821 us; speedup vs baseline: 1.0687x; 1.0687x over previous
//
#include <hip/hip_runtime.h>

#define SEG 24
#define DD  32
#define HEPS 1e-7f
#define N_ITERS 10

typedef _Float16 h2 __attribute__((ext_vector_type(2)));
typedef __fp16   f16v2 __attribute__((ext_vector_type(2)));

__device__ __forceinline__ float frcp(float x) { return __builtin_amdgcn_rcpf(x); }

__device__ __forceinline__ float qx1(float x) {
    return __int_as_float(__builtin_amdgcn_mov_dpp(__float_as_int(x), 0xB1, 0xF, 0xF, true));
}
__device__ __forceinline__ float qx2(float x) {
    return __int_as_float(__builtin_amdgcn_mov_dpp(__float_as_int(x), 0x4E, 0xF, 0xF, true));
}
__device__ __forceinline__ float qsum(float x) {
    x += qx1(x);
    x += qx2(x);
    return x;
}

__device__ __forceinline__ float acosh_coef(float a) {
    float am = fmaf(a, a, -1.0f);
    float s  = sqrtf(am);
    return __logf(a + s) * frcp(s);
}

__device__ __forceinline__ float edot8(const float a[8], const float b[8]) {
    float x = fmaf(a[0], b[0], a[1] * b[1]);
    float y = fmaf(a[2], b[2], a[3] * b[3]);
    float z = fmaf(a[4], b[4], a[5] * b[5]);
    float w = fmaf(a[6], b[6], a[7] * b[7]);
    return qsum((x + y) + (z + w));
}

__device__ __forceinline__ unsigned pk_u32(float a, float b) {
    union { f16v2 f; unsigned u; } c;
    c.f = __builtin_amdgcn_cvt_pkrtz(a, b);
    return c.u;
}
__device__ __forceinline__ h2 pk_h2(float a, float b) {
    union { f16v2 f; h2 h; } c;
    c.f = __builtin_amdgcn_cvt_pkrtz(a, b);
    return c.h;
}
__device__ __forceinline__ h2 as_h2(unsigned u) {
    union { unsigned u; h2 h; } c; c.u = u; return c.h;
}

// ws layout (dwords): [0,1536) packed W f16x2 (s*384 + row*12 + j)
//                     [1536,1664) b f32 (s*32 + d) ; [1664] tanh(es)
#define WS_B_OFF 1536
#define WS_TS_OFF 1664

// ============ K0: pack W to f16x2, copy b, tanh(es) -> d_ws =================
__global__ __launch_bounds__(256)
void prep_kernel(const float* __restrict__ W0, const float* __restrict__ b0,
                 const float* __restrict__ W1, const float* __restrict__ b1,
                 const float* __restrict__ W2, const float* __restrict__ b2,
                 const float* __restrict__ W3, const float* __restrict__ b3,
                 const float* __restrict__ es, unsigned* __restrict__ ws)
{
    const int t = blockIdx.x * blockDim.x + threadIdx.x;
    const float* Ws[4] = { W0, W1, W2, W3 };
    const float* bs[4] = { b0, b1, b2, b3 };
    if (t < 1536) {
        int s = t / 384, rem = t % 384, r = rem / 12, j = rem % 12;
        float a = Ws[s][r * SEG + 2 * j];
        float b = Ws[s][r * SEG + 2 * j + 1];
        ws[t] = pk_u32(a, b);
    } else if (t < 1664) {
        int p = t - 1536;
        reinterpret_cast<float*>(ws)[WS_B_OFF + p] = bs[p / 32][p % 32];
    } else if (t == 1664) {
        reinterpret_cast<float*>(ws)[WS_TS_OFF] = tanhf(es[0]);
    }
}

// ============ K1: encode; float4-granular LDS x-stage + LDS h-stage =========
__global__ __launch_bounds__(256)
void encode_kernel(const float* __restrict__ x0, const float* __restrict__ x1,
                   const float* __restrict__ x2, const float* __restrict__ x3,
                   const unsigned* __restrict__ ws,
                   float* __restrict__ out, int n_items)
{
    __shared__ float lds[256 * DD];   // 32 KB; x-stage uses 28 KB, then h-stage

    const int tid   = threadIdx.x;
    const int item0 = blockIdx.x * 256;
    const int item  = item0 + tid;
    const int s     = blockIdx.y;                   // wave-uniform stream id

    const float* xp;
    if      (s == 0) xp = x0;
    else if (s == 1) xp = x1;
    else if (s == 2) xp = x2;
    else             xp = x3;

    const unsigned* W2p = ws + (size_t)s * 384;     // s_load source
    const float*    B2p = reinterpret_cast<const float*>(ws) + WS_B_OFF + s * 32;
    const float     ts  = reinterpret_cast<const float*>(ws)[WS_TS_OFF];

    // ---- phase A: dense float4 x load -> LDS slots item*7+off (pad 6->7) --
    {
        const float4* xb4 = reinterpret_cast<const float4*>(xp + (size_t)item0 * SEG);
        float4* l4 = reinterpret_cast<float4*>(lds);
        const int nvalid = min(256, n_items - item0);   // full blocks: 256
        #pragma unroll
        for (int c = 0; c < 6; ++c) {
            int f   = c * 256 + tid;                    // 0..1535, dense
            int it  = f / 6;
            int off = f - it * 6;
            if (it < nvalid) l4[it * 7 + off] = xb4[f];
        }
    }
    __syncthreads();

    const bool active = (item < n_items);
    float u[DD];

    if (active) {
        // ---- phase B: seg via 6x ds_read_b128, stride-7 slots (no conflict)
        float seg[SEG];
        {
            const float4* l4 = reinterpret_cast<const float4*>(lds);
            #pragma unroll
            for (int j = 0; j < 6; ++j) {
                float4 v = l4[tid * 7 + j];
                seg[4*j+0] = v.x; seg[4*j+1] = v.y;
                seg[4*j+2] = v.z; seg[4*j+3] = v.w;
            }
        }

        h2 sp2[SEG / 2];
        #pragma unroll
        for (int j = 0; j < SEG / 2; ++j)
            sp2[j] = pk_h2(seg[2*j], seg[2*j+1]);

        #pragma unroll
        for (int d = 0; d < DD; ++d) {
            float z = B2p[d];                        // wave-uniform -> s_load
            #pragma unroll
            for (int j = 0; j < SEG / 2; ++j)
                z = __builtin_amdgcn_fdot2(sp2[j], as_h2(W2p[d * 12 + j]), z, false);
            u[d] = z * ts;
        }

        // <u,u>_L = sum(u^2) - 2*u0^2, 4-way partials
        float q0 = 0.f, q1 = 0.f, q2 = 0.f, q3 = 0.f;
        #pragma unroll
        for (int d = 0; d < DD; d += 4) {
            q0 = fmaf(u[d+0], u[d+0], q0);
            q1 = fmaf(u[d+1], u[d+1], q1);
            q2 = fmaf(u[d+2], u[d+2], q2);
            q3 = fmaf(u[d+3], u[d+3], q3);
        }
        float sq = (q0 + q1) + (q2 + q3) - 2.0f * u[0] * u[0];
        sq = fmaxf(sq, 1e-12f);
        float nrm = sqrtf(sq);
        float ep = __expf(nrm), em = frcp(ep);
        float sh = 0.5f * (ep - em);
        float sc = sh * frcp(fmaxf(nrm, HEPS));

        float r0 = 0.f, r1 = 0.f, r2 = 0.f, r3 = 0.f;
        #pragma unroll
        for (int d = 1; d < DD; ++d) {
            float yv = sc * u[d];
            u[d] = yv;
            if ((d & 3) == 0) r0 = fmaf(yv, yv, r0);
            else if ((d & 3) == 1) r1 = fmaf(yv, yv, r1);
            else if ((d & 3) == 2) r2 = fmaf(yv, yv, r2);
            else r3 = fmaf(yv, yv, r3);
        }
        u[0] = sqrtf(1.0f + (r0 + r1) + (r2 + r3));  // projx time component
    }

    __syncthreads();   // all x reads done; LDS now reused for h staging

    if (active) {
        // swizzled LDS write: float4 slot q = tid*8 + (j ^ (tid&7))
        #pragma unroll
        for (int j = 0; j < DD / 4; ++j) {
            int q = tid * 8 + (j ^ (tid & 7));
            reinterpret_cast<float4*>(lds)[q] =
                make_float4(u[4*j+0], u[4*j+1], u[4*j+2], u[4*j+3]);
        }
    }

    __syncthreads();

    // cooperative dense store: 2048 float4 contiguous
    float4* obase = reinterpret_cast<float4*>(
        out + (size_t)s * ((size_t)n_items * DD) + (size_t)item0 * DD);
    #pragma unroll
    for (int c = 0; c < 8; ++c) {
        int f4   = c * 256 + tid;
        int it_r = f4 >> 3;
        int j    = tid & 7;
        if (item0 + it_r < n_items) {
            int q = it_r * 8 + (j ^ (it_r & 7));
            obase[f4] = reinterpret_cast<const float4*>(lds)[q];
        }
    }
}

// ============ K2: fusion, 4 lanes per item; h in registers, single read =====
#define GMV(o0,o1,o2,o3,o4, v0,v1,v2,v3,v4)                                   \
    o0 = fmaf(G00,(v0), fmaf(G01,(v1), fmaf(G02,(v2), fmaf(G03,(v3), nt0*(v4))))); \
    o1 = fmaf(G01,(v0), fmaf(G11,(v1), fmaf(G12,(v2), fmaf(G13,(v3), nt1*(v4))))); \
    o2 = fmaf(G02,(v0), fmaf(G12,(v1), fmaf(G22,(v2), fmaf(G23,(v3), nt2*(v4))))); \
    o3 = fmaf(G03,(v0), fmaf(G13,(v1), fmaf(G23,(v2), fmaf(G33,(v3), nt3*(v4))))); \
    o4 = fmaf(nt0,(v0), fmaf(nt1,(v1), fmaf(nt2,(v2), fmaf(nt3,(v3), -(v4)))));

#define DOT5(a0,a1,a2,a3,a4, c0,c1,c2,c3,c4) \
    fmaf((a0),(c0), fmaf((a1),(c1), fmaf((a2),(c2), fmaf((a3),(c3), (a4)*(c4)))))

__global__ __launch_bounds__(256)
void fusion_kernel(const float* __restrict__ lw,
                   float* __restrict__ out, int n_items)
{
    const int T    = blockIdx.x * blockDim.x + threadIdx.x;
    const int item = T >> 2;
    const int sub  = T & 3;
    if (item >= n_items) return;

    float l0 = lw[0], l1 = lw[1], l2 = lw[2], l3 = lw[3];
    float mxw = fmaxf(fmaxf(l0, l1), fmaxf(l2, l3));
    float e0 = __expf(l0 - mxw), e1 = __expf(l1 - mxw),
          e2 = __expf(l2 - mxw), e3 = __expf(l3 - mxw);
    float winv = frcp(e0 + e1 + e2 + e3);
    float w0 = e0 * winv, w1 = e1 * winv, w2 = e2 * winv, w3 = e3 * winv;

    const size_t osz = (size_t)n_items * DD;

    float hv[4][8];
    #pragma unroll
    for (int s = 0; s < 4; ++s) {
        const float4* p = reinterpret_cast<const float4*>(
            out + (size_t)s * osz + (size_t)item * DD + sub * 8);
        float4 a = p[0], b = p[1];
        hv[s][0] = a.x; hv[s][1] = a.y; hv[s][2] = a.z; hv[s][3] = a.w;
        hv[s][4] = b.x; hv[s][5] = b.y; hv[s][6] = b.z; hv[s][7] = b.w;
    }

    const float is0 = (sub == 0) ? 1.0f : 0.0f;
    float tau0 = qsum(is0 * hv[0][0]);
    float tau1 = qsum(is0 * hv[1][0]);
    float tau2 = qsum(is0 * hv[2][0]);
    float tau3 = qsum(is0 * hv[3][0]);

    float d00 = edot8(hv[0], hv[0]);
    float d01 = edot8(hv[0], hv[1]);
    float d02 = edot8(hv[0], hv[2]);
    float d03 = edot8(hv[0], hv[3]);
    float d11 = edot8(hv[1], hv[1]);
    float d12 = edot8(hv[1], hv[2]);
    float d13 = edot8(hv[1], hv[3]);
    float d22 = edot8(hv[2], hv[2]);
    float d23 = edot8(hv[2], hv[3]);
    float d33 = edot8(hv[3], hv[3]);

    float G00 = fmaf(-2.0f*tau0, tau0, d00);
    float G01 = fmaf(-2.0f*tau0, tau1, d01);
    float G02 = fmaf(-2.0f*tau0, tau2, d02);
    float G03 = fmaf(-2.0f*tau0, tau3, d03);
    float G11 = fmaf(-2.0f*tau1, tau1, d11);
    float G12 = fmaf(-2.0f*tau1, tau2, d12);
    float G13 = fmaf(-2.0f*tau1, tau3, d13);
    float G22 = fmaf(-2.0f*tau2, tau2, d22);
    float G23 = fmaf(-2.0f*tau2, tau3, d23);
    float G33 = fmaf(-2.0f*tau3, tau3, d33);
    float nt0 = -tau0, nt1 = -tau1, nt2 = -tau2, nt3 = -tau3;

    float b0v, b1v, b2v, b3v, b4v, g0, g1, g2, g3, g4;
    {
        float al0 = fmaxf(tau0, 1.0f + HEPS);
        float al1 = fmaxf(tau1, 1.0f + HEPS);
        float al2 = fmaxf(tau2, 1.0f + HEPS);
        float al3 = fmaxf(tau3, 1.0f + HEPS);
        float cc0 = w0 * acosh_coef(al0);
        float cc1 = w1 * acosh_coef(al1);
        float cc2 = w2 * acosh_coef(al2);
        float cc3 = w3 * acosh_coef(al3);
        b0v = cc0; b1v = cc1; b2v = cc2; b3v = cc3;
        b4v = -DOT5(cc0, cc1, cc2, cc3, 0.0f, al0, al1, al2, al3, 0.0f);

        GMV(g0, g1, g2, g3, g4, b0v, b1v, b2v, b3v, b4v);
        float gq = DOT5(g0, g1, g2, g3, g4, b0v, b1v, b2v, b3v, b4v);
        float sq = fmaxf(gq, 1e-12f);
        float nrm = sqrtf(sq);
        float ep = __expf(nrm), em = frcp(ep);
        float ch = 0.5f * (ep + em);
        float sc = 0.5f * (ep - em) * frcp(fmaxf(nrm, HEPS));
        b0v *= sc; b1v *= sc; b2v *= sc; b3v *= sc;
        b4v = fmaf(sc, b4v, ch);

        GMV(g0, g1, g2, g3, g4, b0v, b1v, b2v, b3v, b4v);
        float xx = DOT5(g0, g1, g2, g3, g4, b0v, b1v, b2v, b3v, b4v);
        float xt = DOT5(b0v, b1v, b2v, b3v, b4v, tau0, tau1, tau2, tau3, 1.0f);
        float tc = sqrtf(fmaf(xt, xt, 1.0f + xx));
        float dl = tc - xt;
        b4v += dl;
        g0 = fmaf(dl, nt0, g0); g1 = fmaf(dl, nt1, g1);
        g2 = fmaf(dl, nt2, g2); g3 = fmaf(dl, nt3, g3);
        g4 -= dl;
    }

    for (int it = 0; it < N_ITERS; ++it) {
        float al0 = fmaxf(-g0, 1.0f + HEPS);
        float al1 = fmaxf(-g1, 1.0f + HEPS);
        float al2 = fmaxf(-g2, 1.0f + HEPS);
        float al3 = fmaxf(-g3, 1.0f + HEPS);
        float cc0 = w0 * acosh_coef(al0);
        float cc1 = w1 * acosh_coef(al1);
        float cc2 = w2 * acosh_coef(al2);
        float cc3 = w3 * acosh_coef(al3);
        float S = DOT5(cc0, cc1, cc2, cc3, 0.0f, al0, al1, al2, al3, 0.0f);

        float gm0 = fmaf(-S, b0v, cc0);
        float gm1 = fmaf(-S, b1v, cc1);
        float gm2 = fmaf(-S, b2v, cc2);
        float gm3 = fmaf(-S, b3v, cc3);
        float gm4 = -S * b4v;

        float Gg0, Gg1, Gg2, Gg3, Gg4;
        GMV(Gg0, Gg1, Gg2, Gg3, Gg4, gm0, gm1, gm2, gm3, gm4);
        float qq = DOT5(Gg0, Gg1, Gg2, Gg3, Gg4, gm0, gm1, gm2, gm3, gm4);

        float sq = fmaxf(0.25f * qq, 1e-12f);
        float nrm = sqrtf(sq);
        float ep = __expf(nrm), em = frcp(ep);
        float ch = 0.5f * (ep + em);
        float sc = 0.25f * (ep - em) * frcp(fmaxf(nrm, HEPS));

        b0v = fmaf(ch, b0v, sc * gm0);
        b1v = fmaf(ch, b1v, sc * gm1);
        b2v = fmaf(ch, b2v, sc * gm2);
        b3v = fmaf(ch, b3v, sc * gm3);
        b4v = fmaf(ch, b4v, sc * gm4);
        g0  = fmaf(ch, g0, sc * Gg0);
        g1  = fmaf(ch, g1, sc * Gg1);
        g2  = fmaf(ch, g2, sc * Gg2);
        g3  = fmaf(ch, g3, sc * Gg3);
        g4  = fmaf(ch, g4, sc * Gg4);

        float xx = DOT5(g0, g1, g2, g3, g4, b0v, b1v, b2v, b3v, b4v);
        float xt = DOT5(b0v, b1v, b2v, b3v, b4v, tau0, tau1, tau2, tau3, 1.0f);
        float tc = sqrtf(fmaf(xt, xt, 1.0f + xx));
        float dl = tc - xt;
        b4v += dl;
        g0 = fmaf(dl, nt0, g0); g1 = fmaf(dl, nt1, g1);
        g2 = fmaf(dl, nt2, g2); g3 = fmaf(dl, nt3, g3);
        g4 -= dl;
    }

    float r[8];
    #pragma unroll
    for (int j = 0; j < 8; ++j)
        r[j] = fmaf(b0v, hv[0][j], fmaf(b1v, hv[1][j],
               fmaf(b2v, hv[2][j], b3v * hv[3][j])));
    if (sub == 0) r[0] += b4v;

    float4* po = reinterpret_cast<float4*>(
        out + (size_t)4 * osz + (size_t)item * DD + sub * 8);
    po[0] = make_float4(r[0], r[1], r[2], r[3]);
    po[1] = make_float4(r[4], r[5], r[6], r[7]);
}

extern "C" void kernel_launch(void* const* d_in, const int* in_sizes, int n_in,
                              void* d_out, int out_size, void* d_ws, size_t ws_size,
                              hipStream_t stream)
{
    const float* x0 = (const float*)d_in[0];
    const float* x1 = (const float*)d_in[1];
    const float* x2 = (const float*)d_in[2];
    const float* x3 = (const float*)d_in[3];
    const float* W0 = (const float*)d_in[4];
    const float* b0 = (const float*)d_in[5];
    const float* W1 = (const float*)d_in[6];
    const float* b1 = (const float*)d_in[7];
    const float* W2 = (const float*)d_in[8];
    const float* b2 = (const float*)d_in[9];
    const float* W3 = (const float*)d_in[10];
    const float* b3 = (const float*)d_in[11];
    const float* es = (const float*)d_in[12];
    const float* lw = (const float*)d_in[13];

    const int n_items = in_sizes[0] / SEG;   // 262144
    const int block = 256;

    prep_kernel<<<7, block, 0, stream>>>(W0, b0, W1, b1, W2, b2, W3, b3,
                                         es, (unsigned*)d_ws);

    const int gx = (n_items + block - 1) / block;
    dim3 grid1(gx, 4, 1);
    encode_kernel<<<grid1, block, 0, stream>>>(x0, x1, x2, x3,
                                               (const unsigned*)d_ws,
                                               (float*)d_out, n_items);

    const int n_threads = n_items * 4;
    const int gx2 = (n_threads + block - 1) / block;
    fusion_kernel<<<gx2, block, 0, stream>>>(lw, (float*)d_out, n_items);
}

// Round 14
// 119.934 us; speedup vs baseline: 1.3171x; 1.2325x over previous
//
#include <hip/hip_runtime.h>

#define SEG 24
#define DD  32
#define HEPS 1e-7f
#define N_ITERS 10
#define IPB 64                         // items per block

typedef _Float16 h2 __attribute__((ext_vector_type(2)));
typedef __fp16   f16v2 __attribute__((ext_vector_type(2)));

__device__ __forceinline__ float frcp(float x) { return __builtin_amdgcn_rcpf(x); }

__device__ __forceinline__ float qx1(float x) {
    return __int_as_float(__builtin_amdgcn_mov_dpp(__float_as_int(x), 0xB1, 0xF, 0xF, true));
}
__device__ __forceinline__ float qx2(float x) {
    return __int_as_float(__builtin_amdgcn_mov_dpp(__float_as_int(x), 0x4E, 0xF, 0xF, true));
}
__device__ __forceinline__ float qsum(float x) {
    x += qx1(x);
    x += qx2(x);
    return x;
}

__device__ __forceinline__ float acosh_coef(float a) {
    float am = fmaf(a, a, -1.0f);
    float s  = sqrtf(am);
    return __logf(a + s) * frcp(s);
}

__device__ __forceinline__ float edot8(const float a[8], const float b[8]) {
    float x = fmaf(a[0], b[0], a[1] * b[1]);
    float y = fmaf(a[2], b[2], a[3] * b[3]);
    float z = fmaf(a[4], b[4], a[5] * b[5]);
    float w = fmaf(a[6], b[6], a[7] * b[7]);
    return qsum((x + y) + (z + w));
}

__device__ __forceinline__ unsigned pk_u32(float a, float b) {
    union { f16v2 f; unsigned u; } c;
    c.f = __builtin_amdgcn_cvt_pkrtz(a, b);
    return c.u;
}
__device__ __forceinline__ h2 pk_h2(float a, float b) {
    union { f16v2 f; h2 h; } c;
    c.f = __builtin_amdgcn_cvt_pkrtz(a, b);
    return c.h;
}
__device__ __forceinline__ h2 as_h2(unsigned u) {
    union { unsigned u; h2 h; } c; c.u = u; return c.h;
}

// ws layout (dwords): [0,1536) packed W f16x2 (s*384 + row*12 + j)
//                     [1536,1664) b f32 (s*32 + d) ; [1664] tanh(es)
#define WS_B_OFF 1536
#define WS_TS_OFF 1664

// ============ K0: pack W to f16x2, copy b, tanh(es) -> d_ws =================
__global__ __launch_bounds__(256)
void prep_kernel(const float* __restrict__ W0, const float* __restrict__ b0,
                 const float* __restrict__ W1, const float* __restrict__ b1,
                 const float* __restrict__ W2, const float* __restrict__ b2,
                 const float* __restrict__ W3, const float* __restrict__ b3,
                 const float* __restrict__ es, unsigned* __restrict__ ws)
{
    const int t = blockIdx.x * blockDim.x + threadIdx.x;
    const float* Ws[4] = { W0, W1, W2, W3 };
    const float* bs[4] = { b0, b1, b2, b3 };
    if (t < 1536) {
        int s = t / 384, rem = t % 384, r = rem / 12, j = rem % 12;
        float a = Ws[s][r * SEG + 2 * j];
        float b = Ws[s][r * SEG + 2 * j + 1];
        ws[t] = pk_u32(a, b);
    } else if (t < 1664) {
        int p = t - 1536;
        reinterpret_cast<float*>(ws)[WS_B_OFF + p] = bs[p / 32][p % 32];
    } else if (t == 1664) {
        reinterpret_cast<float*>(ws)[WS_TS_OFF] = tanhf(es[0]);
    }
}

// ============ K1: fused encode + fusion, f32 LDS hand-off ===================
#define GMV(o0,o1,o2,o3,o4, v0,v1,v2,v3,v4)                                   \
    o0 = fmaf(G00,(v0), fmaf(G01,(v1), fmaf(G02,(v2), fmaf(G03,(v3), nt0*(v4))))); \
    o1 = fmaf(G01,(v0), fmaf(G11,(v1), fmaf(G12,(v2), fmaf(G13,(v3), nt1*(v4))))); \
    o2 = fmaf(G02,(v0), fmaf(G12,(v1), fmaf(G22,(v2), fmaf(G23,(v3), nt2*(v4))))); \
    o3 = fmaf(G03,(v0), fmaf(G13,(v1), fmaf(G23,(v2), fmaf(G33,(v3), nt3*(v4))))); \
    o4 = fmaf(nt0,(v0), fmaf(nt1,(v1), fmaf(nt2,(v2), fmaf(nt3,(v3), -(v4)))));

#define DOT5(a0,a1,a2,a3,a4, c0,c1,c2,c3,c4) \
    fmaf((a0),(c0), fmaf((a1),(c1), fmaf((a2),(c2), fmaf((a3),(c3), (a4)*(c4)))))

__global__ __launch_bounds__(256)
void fused_kernel(const float* __restrict__ x0, const float* __restrict__ x1,
                  const float* __restrict__ x2, const float* __restrict__ x3,
                  const unsigned* __restrict__ ws, const float* __restrict__ lw,
                  float* __restrict__ out, int n_items)
{
    __shared__ float4 lds4[4 * IPB * 8];            // 32 KB, f32 h hand-off

    const int tid   = threadIdx.x;
    const int item0 = blockIdx.x * IPB;
    const size_t osz = (size_t)n_items * DD;

    const float* wsf = reinterpret_cast<const float*>(ws);
    const float  ts  = wsf[WS_TS_OFF];

    // ---------------- phase 1: encode one (item, stream) per thread --------
    {
        const int s1  = tid >> 6;                    // wave-uniform stream id
        const int il1 = tid & 63;
        const int it1 = item0 + il1;

        const float* xp;
        if      (s1 == 0) xp = x0;
        else if (s1 == 1) xp = x1;
        else if (s1 == 2) xp = x2;
        else              xp = x3;

        const unsigned* W2p = ws + (size_t)s1 * 384; // s_load source
        const float*    B2p = wsf + WS_B_OFF + s1 * 32;

        if (it1 < n_items) {
            float seg[SEG];
            const float4* sp = reinterpret_cast<const float4*>(xp + (size_t)it1 * SEG);
            #pragma unroll
            for (int j = 0; j < SEG / 4; ++j) {
                float4 v = sp[j];
                seg[4*j+0] = v.x; seg[4*j+1] = v.y; seg[4*j+2] = v.z; seg[4*j+3] = v.w;
            }
            h2 sp2[SEG / 2];
            #pragma unroll
            for (int j = 0; j < SEG / 2; ++j)
                sp2[j] = pk_h2(seg[2*j], seg[2*j+1]);

            float u[DD];
            #pragma unroll
            for (int d = 0; d < DD; ++d) {
                float z = B2p[d];                    // wave-uniform -> s_load
                #pragma unroll
                for (int j = 0; j < SEG / 2; ++j)
                    z = __builtin_amdgcn_fdot2(sp2[j], as_h2(W2p[d * 12 + j]), z, false);
                u[d] = z * ts;
            }

            float q0 = 0.f, q1 = 0.f, q2 = 0.f, q3 = 0.f;
            #pragma unroll
            for (int d = 0; d < DD; d += 4) {
                q0 = fmaf(u[d+0], u[d+0], q0);
                q1 = fmaf(u[d+1], u[d+1], q1);
                q2 = fmaf(u[d+2], u[d+2], q2);
                q3 = fmaf(u[d+3], u[d+3], q3);
            }
            float sq = (q0 + q1) + (q2 + q3) - 2.0f * u[0] * u[0];
            sq = fmaxf(sq, 1e-12f);
            float nrm = sqrtf(sq);
            float ep = __expf(nrm), em = frcp(ep);
            float sh = 0.5f * (ep - em);
            float sc = sh * frcp(fmaxf(nrm, HEPS));

            float r0 = 0.f, r1 = 0.f, r2 = 0.f, r3 = 0.f;
            #pragma unroll
            for (int d = 1; d < DD; ++d) {
                float yv = sc * u[d];
                u[d] = yv;
                if ((d & 3) == 0) r0 = fmaf(yv, yv, r0);
                else if ((d & 3) == 1) r1 = fmaf(yv, yv, r1);
                else if ((d & 3) == 2) r2 = fmaf(yv, yv, r2);
                else r3 = fmaf(yv, yv, r3);
            }
            u[0] = sqrtf(1.0f + (r0 + r1) + (r2 + r3));  // projx time component

            // swizzled LDS write (f32, no conversion)
            #pragma unroll
            for (int j = 0; j < DD / 4; ++j) {
                int slot = (s1 * IPB + il1) * 8 + (j ^ (il1 & 7));
                lds4[slot] = make_float4(u[4*j+0], u[4*j+1], u[4*j+2], u[4*j+3]);
            }
        }
    }

    __syncthreads();   // LDS is only READ from here on — single barrier suffices

    // ---------------- phase 1.5: cooperative dense h store -----------------
    #pragma unroll
    for (int c = 0; c < 8; ++c) {
        int f   = c * 256 + tid;                     // 0..2047
        int s   = f >> 9;                            // uniform per (c, wave)
        int rem = f & 511;                           // float4 idx in stream chunk
        int it  = rem >> 3;
        int j   = rem & 7;
        if (item0 + it < n_items) {
            int slot = (s * IPB + it) * 8 + (j ^ (it & 7));
            reinterpret_cast<float4*>(out + (size_t)s * osz + (size_t)item0 * DD)[rem]
                = lds4[slot];
        }
    }

    // ---------------- phase 2: fusion, quad per item from LDS --------------
    const int il2  = tid >> 2;
    const int sub  = tid & 3;
    const int item = item0 + il2;
    if (item >= n_items) return;

    float l0 = lw[0], l1 = lw[1], l2w = lw[2], l3 = lw[3];
    float mxw = fmaxf(fmaxf(l0, l1), fmaxf(l2w, l3));
    float e0 = __expf(l0 - mxw), e1 = __expf(l1 - mxw),
          e2 = __expf(l2w - mxw), e3 = __expf(l3 - mxw);
    float winv = frcp(e0 + e1 + e2 + e3);
    float w0 = e0 * winv, w1 = e1 * winv, w2 = e2 * winv, w3 = e3 * winv;

    float hv[4][8];
    #pragma unroll
    for (int s = 0; s < 4; ++s) {
        float4 a = lds4[(s * IPB + il2) * 8 + ((2*sub)     ^ (il2 & 7))];
        float4 b = lds4[(s * IPB + il2) * 8 + ((2*sub + 1) ^ (il2 & 7))];
        hv[s][0] = a.x; hv[s][1] = a.y; hv[s][2] = a.z; hv[s][3] = a.w;
        hv[s][4] = b.x; hv[s][5] = b.y; hv[s][6] = b.z; hv[s][7] = b.w;
    }

    const float is0 = (sub == 0) ? 1.0f : 0.0f;
    float tau0 = qsum(is0 * hv[0][0]);
    float tau1 = qsum(is0 * hv[1][0]);
    float tau2 = qsum(is0 * hv[2][0]);
    float tau3 = qsum(is0 * hv[3][0]);

    float d00 = edot8(hv[0], hv[0]);
    float d01 = edot8(hv[0], hv[1]);
    float d02 = edot8(hv[0], hv[2]);
    float d03 = edot8(hv[0], hv[3]);
    float d11 = edot8(hv[1], hv[1]);
    float d12 = edot8(hv[1], hv[2]);
    float d13 = edot8(hv[1], hv[3]);
    float d22 = edot8(hv[2], hv[2]);
    float d23 = edot8(hv[2], hv[3]);
    float d33 = edot8(hv[3], hv[3]);

    float G00 = fmaf(-2.0f*tau0, tau0, d00);
    float G01 = fmaf(-2.0f*tau0, tau1, d01);
    float G02 = fmaf(-2.0f*tau0, tau2, d02);
    float G03 = fmaf(-2.0f*tau0, tau3, d03);
    float G11 = fmaf(-2.0f*tau1, tau1, d11);
    float G12 = fmaf(-2.0f*tau1, tau2, d12);
    float G13 = fmaf(-2.0f*tau1, tau3, d13);
    float G22 = fmaf(-2.0f*tau2, tau2, d22);
    float G23 = fmaf(-2.0f*tau2, tau3, d23);
    float G33 = fmaf(-2.0f*tau3, tau3, d33);
    float nt0 = -tau0, nt1 = -tau1, nt2 = -tau2, nt3 = -tau3;

    float b0v, b1v, b2v, b3v, b4v, g0, g1, g2, g3, g4;
    {
        float al0 = fmaxf(tau0, 1.0f + HEPS);
        float al1 = fmaxf(tau1, 1.0f + HEPS);
        float al2 = fmaxf(tau2, 1.0f + HEPS);
        float al3 = fmaxf(tau3, 1.0f + HEPS);
        float cc0 = w0 * acosh_coef(al0);
        float cc1 = w1 * acosh_coef(al1);
        float cc2 = w2 * acosh_coef(al2);
        float cc3 = w3 * acosh_coef(al3);
        b0v = cc0; b1v = cc1; b2v = cc2; b3v = cc3;
        b4v = -DOT5(cc0, cc1, cc2, cc3, 0.0f, al0, al1, al2, al3, 0.0f);

        GMV(g0, g1, g2, g3, g4, b0v, b1v, b2v, b3v, b4v);
        float gq = DOT5(g0, g1, g2, g3, g4, b0v, b1v, b2v, b3v, b4v);
        float sq = fmaxf(gq, 1e-12f);
        float nrm = sqrtf(sq);
        float ep = __expf(nrm), em = frcp(ep);
        float ch = 0.5f * (ep + em);
        float sc = 0.5f * (ep - em) * frcp(fmaxf(nrm, HEPS));
        b0v *= sc; b1v *= sc; b2v *= sc; b3v *= sc;
        b4v = fmaf(sc, b4v, ch);

        GMV(g0, g1, g2, g3, g4, b0v, b1v, b2v, b3v, b4v);
        float xx = DOT5(g0, g1, g2, g3, g4, b0v, b1v, b2v, b3v, b4v);
        float xt = DOT5(b0v, b1v, b2v, b3v, b4v, tau0, tau1, tau2, tau3, 1.0f);
        float tc = sqrtf(fmaf(xt, xt, 1.0f + xx));
        float dl = tc - xt;
        b4v += dl;
        g0 = fmaf(dl, nt0, g0); g1 = fmaf(dl, nt1, g1);
        g2 = fmaf(dl, nt2, g2); g3 = fmaf(dl, nt3, g3);
        g4 -= dl;
    }

    for (int it = 0; it < N_ITERS; ++it) {
        float al0 = fmaxf(-g0, 1.0f + HEPS);
        float al1 = fmaxf(-g1, 1.0f + HEPS);
        float al2 = fmaxf(-g2, 1.0f + HEPS);
        float al3 = fmaxf(-g3, 1.0f + HEPS);
        float cc0 = w0 * acosh_coef(al0);
        float cc1 = w1 * acosh_coef(al1);
        float cc2 = w2 * acosh_coef(al2);
        float cc3 = w3 * acosh_coef(al3);
        float S = DOT5(cc0, cc1, cc2, cc3, 0.0f, al0, al1, al2, al3, 0.0f);

        float gm0 = fmaf(-S, b0v, cc0);
        float gm1 = fmaf(-S, b1v, cc1);
        float gm2 = fmaf(-S, b2v, cc2);
        float gm3 = fmaf(-S, b3v, cc3);
        float gm4 = -S * b4v;

        float Gg0, Gg1, Gg2, Gg3, Gg4;
        GMV(Gg0, Gg1, Gg2, Gg3, Gg4, gm0, gm1, gm2, gm3, gm4);
        float qq = DOT5(Gg0, Gg1, Gg2, Gg3, Gg4, gm0, gm1, gm2, gm3, gm4);

        float sq = fmaxf(0.25f * qq, 1e-12f);
        float nrm = sqrtf(sq);
        float ep = __expf(nrm), em = frcp(ep);
        float ch = 0.5f * (ep + em);
        float sc = 0.25f * (ep - em) * frcp(fmaxf(nrm, HEPS));

        b0v = fmaf(ch, b0v, sc * gm0);
        b1v = fmaf(ch, b1v, sc * gm1);
        b2v = fmaf(ch, b2v, sc * gm2);
        b3v = fmaf(ch, b3v, sc * gm3);
        b4v = fmaf(ch, b4v, sc * gm4);
        g0  = fmaf(ch, g0, sc * Gg0);
        g1  = fmaf(ch, g1, sc * Gg1);
        g2  = fmaf(ch, g2, sc * Gg2);
        g3  = fmaf(ch, g3, sc * Gg3);
        g4  = fmaf(ch, g4, sc * Gg4);

        float xx = DOT5(g0, g1, g2, g3, g4, b0v, b1v, b2v, b3v, b4v);
        float xt = DOT5(b0v, b1v, b2v, b3v, b4v, tau0, tau1, tau2, tau3, 1.0f);
        float tc = sqrtf(fmaf(xt, xt, 1.0f + xx));
        float dl = tc - xt;
        b4v += dl;
        g0 = fmaf(dl, nt0, g0); g1 = fmaf(dl, nt1, g1);
        g2 = fmaf(dl, nt2, g2); g3 = fmaf(dl, nt3, g3);
        g4 -= dl;
    }

    float r[8];
    #pragma unroll
    for (int j = 0; j < 8; ++j)
        r[j] = fmaf(b0v, hv[0][j], fmaf(b1v, hv[1][j],
               fmaf(b2v, hv[2][j], b3v * hv[3][j])));
    if (sub == 0) r[0] += b4v;

    float4* po = reinterpret_cast<float4*>(
        out + (size_t)4 * osz + (size_t)item * DD + sub * 8);
    po[0] = make_float4(r[0], r[1], r[2], r[3]);
    po[1] = make_float4(r[4], r[5], r[6], r[7]);
}

extern "C" void kernel_launch(void* const* d_in, const int* in_sizes, int n_in,
                              void* d_out, int out_size, void* d_ws, size_t ws_size,
                              hipStream_t stream)
{
    const float* x0 = (const float*)d_in[0];
    const float* x1 = (const float*)d_in[1];
    const float* x2 = (const float*)d_in[2];
    const float* x3 = (const float*)d_in[3];
    const float* W0 = (const float*)d_in[4];
    const float* b0 = (const float*)d_in[5];
    const float* W1 = (const float*)d_in[6];
    const float* b1 = (const float*)d_in[7];
    const float* W2 = (const float*)d_in[8];
    const float* b2 = (const float*)d_in[9];
    const float* W3 = (const float*)d_in[10];
    const float* b3 = (const float*)d_in[11];
    const float* es = (const float*)d_in[12];
    const float* lw = (const float*)d_in[13];

    const int n_items = in_sizes[0] / SEG;   // 262144
    prep_kernel<<<7, 256, 0, stream>>>(W0, b0, W1, b1, W2, b2, W3, b3,
                                       es, (unsigned*)d_ws);

    const int gx = (n_items + IPB - 1) / IPB;       // 4096
    fused_kernel<<<gx, 256, 0, stream>>>(x0, x1, x2, x3,
                                         (const unsigned*)d_ws, lw,
                                         (float*)d_out, n_items);
}

// Round 15
// 100.225 us; speedup vs baseline: 1.5761x; 1.1966x over previous
//
#include <hip/hip_runtime.h>

#define SEG 24
#define DD  32
#define HEPS 1e-7f
#define N_ITERS 10
#define IPB 64                         // items per block

typedef _Float16 h2 __attribute__((ext_vector_type(2)));
typedef __fp16   f16v2 __attribute__((ext_vector_type(2)));

__device__ __forceinline__ float frcp(float x) { return __builtin_amdgcn_rcpf(x); }

__device__ __forceinline__ float qx1(float x) {
    return __int_as_float(__builtin_amdgcn_mov_dpp(__float_as_int(x), 0xB1, 0xF, 0xF, true));
}
__device__ __forceinline__ float qx2(float x) {
    return __int_as_float(__builtin_amdgcn_mov_dpp(__float_as_int(x), 0x4E, 0xF, 0xF, true));
}
__device__ __forceinline__ float qsum(float x) {
    x += qx1(x);
    x += qx2(x);
    return x;
}

__device__ __forceinline__ float acosh_coef(float a) {
    float am = fmaf(a, a, -1.0f);
    float s  = sqrtf(am);
    return __logf(a + s) * frcp(s);
}

__device__ __forceinline__ float edot8(const float a[8], const float b[8]) {
    float x = fmaf(a[0], b[0], a[1] * b[1]);
    float y = fmaf(a[2], b[2], a[3] * b[3]);
    float z = fmaf(a[4], b[4], a[5] * b[5]);
    float w = fmaf(a[6], b[6], a[7] * b[7]);
    return qsum((x + y) + (z + w));
}

__device__ __forceinline__ unsigned pk_u32(float a, float b) {
    union { f16v2 f; unsigned u; } c;
    c.f = __builtin_amdgcn_cvt_pkrtz(a, b);
    return c.u;
}
__device__ __forceinline__ h2 pk_h2(float a, float b) {
    union { f16v2 f; h2 h; } c;
    c.f = __builtin_amdgcn_cvt_pkrtz(a, b);
    return c.h;
}
__device__ __forceinline__ h2 as_h2(unsigned u) {
    union { unsigned u; h2 h; } c; c.u = u; return c.h;
}

// ws layout (dwords): [0,1536) packed W f16x2 (s*384 + row*12 + j)
//                     [1536,1664) b f32 (s*32 + d) ; [1664] tanh(es)
#define WS_B_OFF 1536
#define WS_TS_OFF 1664

// ============ K0: pack W to f16x2, copy b, tanh(es) -> d_ws =================
__global__ __launch_bounds__(256)
void prep_kernel(const float* __restrict__ W0, const float* __restrict__ b0,
                 const float* __restrict__ W1, const float* __restrict__ b1,
                 const float* __restrict__ W2, const float* __restrict__ b2,
                 const float* __restrict__ W3, const float* __restrict__ b3,
                 const float* __restrict__ es, unsigned* __restrict__ ws)
{
    const int t = blockIdx.x * blockDim.x + threadIdx.x;
    const float* Ws[4] = { W0, W1, W2, W3 };
    const float* bs[4] = { b0, b1, b2, b3 };
    if (t < 1536) {
        int s = t / 384, rem = t % 384, r = rem / 12, j = rem % 12;
        float a = Ws[s][r * SEG + 2 * j];
        float b = Ws[s][r * SEG + 2 * j + 1];
        ws[t] = pk_u32(a, b);
    } else if (t < 1664) {
        int p = t - 1536;
        reinterpret_cast<float*>(ws)[WS_B_OFF + p] = bs[p / 32][p % 32];
    } else if (t == 1664) {
        reinterpret_cast<float*>(ws)[WS_TS_OFF] = tanhf(es[0]);
    }
}

// ============ K1: fused; quad Gram + one-lane-per-item 5-d loop =============
#define GMV(o0,o1,o2,o3,o4, v0,v1,v2,v3,v4)                                   \
    o0 = fmaf(G00,(v0), fmaf(G01,(v1), fmaf(G02,(v2), fmaf(G03,(v3), nt0*(v4))))); \
    o1 = fmaf(G01,(v0), fmaf(G11,(v1), fmaf(G12,(v2), fmaf(G13,(v3), nt1*(v4))))); \
    o2 = fmaf(G02,(v0), fmaf(G12,(v1), fmaf(G22,(v2), fmaf(G23,(v3), nt2*(v4))))); \
    o3 = fmaf(G03,(v0), fmaf(G13,(v1), fmaf(G23,(v2), fmaf(G33,(v3), nt3*(v4))))); \
    o4 = fmaf(nt0,(v0), fmaf(nt1,(v1), fmaf(nt2,(v2), fmaf(nt3,(v3), -(v4)))));

#define DOT5(a0,a1,a2,a3,a4, c0,c1,c2,c3,c4) \
    fmaf((a0),(c0), fmaf((a1),(c1), fmaf((a2),(c2), fmaf((a3),(c3), (a4)*(c4)))))

__global__ __launch_bounds__(256)
void fused_kernel(const float* __restrict__ x0, const float* __restrict__ x1,
                  const float* __restrict__ x2, const float* __restrict__ x3,
                  const unsigned* __restrict__ ws, const float* __restrict__ lw,
                  float* __restrict__ out, int n_items)
{
    __shared__ float4 lds4[4 * IPB * 8];            // 32 KB, f32 h hand-off
    __shared__ float  gstate[IPB][20];              // 5 KB, Gram+tau per item
    __shared__ float  betas[IPB][5];                // 1.25 KB, loop output

    const int tid   = threadIdx.x;
    const int item0 = blockIdx.x * IPB;
    const size_t osz = (size_t)n_items * DD;

    const float* wsf = reinterpret_cast<const float*>(ws);
    const float  ts  = wsf[WS_TS_OFF];

    // ---------------- phase 1: encode one (item, stream) per thread --------
    {
        const int s1  = tid >> 6;                    // wave-uniform stream id
        const int il1 = tid & 63;
        const int it1 = item0 + il1;

        const float* xp;
        if      (s1 == 0) xp = x0;
        else if (s1 == 1) xp = x1;
        else if (s1 == 2) xp = x2;
        else              xp = x3;

        const unsigned* W2p = ws + (size_t)s1 * 384; // s_load source
        const float*    B2p = wsf + WS_B_OFF + s1 * 32;

        if (it1 < n_items) {
            float seg[SEG];
            const float4* sp = reinterpret_cast<const float4*>(xp + (size_t)it1 * SEG);
            #pragma unroll
            for (int j = 0; j < SEG / 4; ++j) {
                float4 v = sp[j];
                seg[4*j+0] = v.x; seg[4*j+1] = v.y; seg[4*j+2] = v.z; seg[4*j+3] = v.w;
            }
            h2 sp2[SEG / 2];
            #pragma unroll
            for (int j = 0; j < SEG / 2; ++j)
                sp2[j] = pk_h2(seg[2*j], seg[2*j+1]);

            float u[DD];
            #pragma unroll
            for (int d = 0; d < DD; ++d) {
                float z = B2p[d];                    // wave-uniform -> s_load
                #pragma unroll
                for (int j = 0; j < SEG / 2; ++j)
                    z = __builtin_amdgcn_fdot2(sp2[j], as_h2(W2p[d * 12 + j]), z, false);
                u[d] = z * ts;
            }

            float q0 = 0.f, q1 = 0.f, q2 = 0.f, q3 = 0.f;
            #pragma unroll
            for (int d = 0; d < DD; d += 4) {
                q0 = fmaf(u[d+0], u[d+0], q0);
                q1 = fmaf(u[d+1], u[d+1], q1);
                q2 = fmaf(u[d+2], u[d+2], q2);
                q3 = fmaf(u[d+3], u[d+3], q3);
            }
            float sq = (q0 + q1) + (q2 + q3) - 2.0f * u[0] * u[0];
            sq = fmaxf(sq, 1e-12f);
            float nrm = sqrtf(sq);
            float ep = __expf(nrm), em = frcp(ep);
            float sh = 0.5f * (ep - em);
            float sc = sh * frcp(fmaxf(nrm, HEPS));

            float r0 = 0.f, r1 = 0.f, r2 = 0.f, r3 = 0.f;
            #pragma unroll
            for (int d = 1; d < DD; ++d) {
                float yv = sc * u[d];
                u[d] = yv;
                if ((d & 3) == 0) r0 = fmaf(yv, yv, r0);
                else if ((d & 3) == 1) r1 = fmaf(yv, yv, r1);
                else if ((d & 3) == 2) r2 = fmaf(yv, yv, r2);
                else r3 = fmaf(yv, yv, r3);
            }
            u[0] = sqrtf(1.0f + (r0 + r1) + (r2 + r3));  // projx time component

            // swizzled LDS write (f32, no conversion)
            #pragma unroll
            for (int j = 0; j < DD / 4; ++j) {
                int slot = (s1 * IPB + il1) * 8 + (j ^ (il1 & 7));
                lds4[slot] = make_float4(u[4*j+0], u[4*j+1], u[4*j+2], u[4*j+3]);
            }
        }
    }

    __syncthreads();

    // ---------------- phase 1.5: cooperative dense h store -----------------
    #pragma unroll
    for (int c = 0; c < 8; ++c) {
        int f   = c * 256 + tid;                     // 0..2047
        int s   = f >> 9;                            // uniform per (c, wave)
        int rem = f & 511;                           // float4 idx in stream chunk
        int it  = rem >> 3;
        int j   = rem & 7;
        if (item0 + it < n_items) {
            int slot = (s * IPB + it) * 8 + (j ^ (it & 7));
            reinterpret_cast<float4*>(out + (size_t)s * osz + (size_t)item0 * DD)[rem]
                = lds4[slot];
        }
    }

    // ---------------- phase 2a: quad-layout hv load + Gram -----------------
    const int il2  = tid >> 2;
    const int sub  = tid & 3;
    const int item = item0 + il2;
    const bool act = (item < n_items);

    float hv[4][8];
    if (act) {
        #pragma unroll
        for (int s = 0; s < 4; ++s) {
            float4 a = lds4[(s * IPB + il2) * 8 + ((2*sub)     ^ (il2 & 7))];
            float4 b = lds4[(s * IPB + il2) * 8 + ((2*sub + 1) ^ (il2 & 7))];
            hv[s][0] = a.x; hv[s][1] = a.y; hv[s][2] = a.z; hv[s][3] = a.w;
            hv[s][4] = b.x; hv[s][5] = b.y; hv[s][6] = b.z; hv[s][7] = b.w;
        }

        const float is0 = (sub == 0) ? 1.0f : 0.0f;
        float tau0 = qsum(is0 * hv[0][0]);
        float tau1 = qsum(is0 * hv[1][0]);
        float tau2 = qsum(is0 * hv[2][0]);
        float tau3 = qsum(is0 * hv[3][0]);

        float d00 = edot8(hv[0], hv[0]);
        float d01 = edot8(hv[0], hv[1]);
        float d02 = edot8(hv[0], hv[2]);
        float d03 = edot8(hv[0], hv[3]);
        float d11 = edot8(hv[1], hv[1]);
        float d12 = edot8(hv[1], hv[2]);
        float d13 = edot8(hv[1], hv[3]);
        float d22 = edot8(hv[2], hv[2]);
        float d23 = edot8(hv[2], hv[3]);
        float d33 = edot8(hv[3], hv[3]);

        if (sub == 0) {
            float4* g4 = reinterpret_cast<float4*>(gstate[il2]);
            g4[0] = make_float4(fmaf(-2.0f*tau0, tau0, d00),
                                fmaf(-2.0f*tau0, tau1, d01),
                                fmaf(-2.0f*tau0, tau2, d02),
                                fmaf(-2.0f*tau0, tau3, d03));
            g4[1] = make_float4(fmaf(-2.0f*tau1, tau1, d11),
                                fmaf(-2.0f*tau1, tau2, d12),
                                fmaf(-2.0f*tau1, tau3, d13),
                                fmaf(-2.0f*tau2, tau2, d22));
            g4[2] = make_float4(fmaf(-2.0f*tau2, tau3, d23),
                                fmaf(-2.0f*tau3, tau3, d33),
                                tau0, tau1);
            g4[3] = make_float4(tau2, tau3, 0.0f, 0.0f);
        }
    }

    __syncthreads();

    // ---------------- phase 2b: 5-d Frechet, ONE lane per item -------------
    if (tid < IPB && (item0 + tid) < n_items) {
        // softmax over lorentz weights (replicated only on this wave)
        float l0 = lw[0], l1 = lw[1], l2w = lw[2], l3 = lw[3];
        float mxw = fmaxf(fmaxf(l0, l1), fmaxf(l2w, l3));
        float e0 = __expf(l0 - mxw), e1 = __expf(l1 - mxw),
              e2 = __expf(l2w - mxw), e3 = __expf(l3 - mxw);
        float winv = frcp(e0 + e1 + e2 + e3);
        float w0 = e0 * winv, w1 = e1 * winv, w2 = e2 * winv, w3 = e3 * winv;

        const float4* g4 = reinterpret_cast<const float4*>(gstate[tid]);
        float4 ga = g4[0], gb = g4[1], gc = g4[2], gd = g4[3];
        float G00 = ga.x, G01 = ga.y, G02 = ga.z, G03 = ga.w;
        float G11 = gb.x, G12 = gb.y, G13 = gb.z, G22 = gb.w;
        float G23 = gc.x, G33 = gc.y;
        float tau0 = gc.z, tau1 = gc.w, tau2 = gd.x, tau3 = gd.y;
        float nt0 = -tau0, nt1 = -tau1, nt2 = -tau2, nt3 = -tau3;

        float b0v, b1v, b2v, b3v, b4v, g0, g1, g2, g3, g4s;
        {
            float al0 = fmaxf(tau0, 1.0f + HEPS);
            float al1 = fmaxf(tau1, 1.0f + HEPS);
            float al2 = fmaxf(tau2, 1.0f + HEPS);
            float al3 = fmaxf(tau3, 1.0f + HEPS);
            float cc0 = w0 * acosh_coef(al0);
            float cc1 = w1 * acosh_coef(al1);
            float cc2 = w2 * acosh_coef(al2);
            float cc3 = w3 * acosh_coef(al3);
            b0v = cc0; b1v = cc1; b2v = cc2; b3v = cc3;
            b4v = -DOT5(cc0, cc1, cc2, cc3, 0.0f, al0, al1, al2, al3, 0.0f);

            GMV(g0, g1, g2, g3, g4s, b0v, b1v, b2v, b3v, b4v);
            float gq = DOT5(g0, g1, g2, g3, g4s, b0v, b1v, b2v, b3v, b4v);
            float sq = fmaxf(gq, 1e-12f);
            float nrm = sqrtf(sq);
            float ep = __expf(nrm), em = frcp(ep);
            float ch = 0.5f * (ep + em);
            float sc = 0.5f * (ep - em) * frcp(fmaxf(nrm, HEPS));
            b0v *= sc; b1v *= sc; b2v *= sc; b3v *= sc;
            b4v = fmaf(sc, b4v, ch);

            GMV(g0, g1, g2, g3, g4s, b0v, b1v, b2v, b3v, b4v);
            float xx = DOT5(g0, g1, g2, g3, g4s, b0v, b1v, b2v, b3v, b4v);
            float xt = DOT5(b0v, b1v, b2v, b3v, b4v, tau0, tau1, tau2, tau3, 1.0f);
            float tc = sqrtf(fmaf(xt, xt, 1.0f + xx));
            float dl = tc - xt;
            b4v += dl;
            g0 = fmaf(dl, nt0, g0); g1 = fmaf(dl, nt1, g1);
            g2 = fmaf(dl, nt2, g2); g3 = fmaf(dl, nt3, g3);
            g4s -= dl;
        }

        for (int it = 0; it < N_ITERS; ++it) {
            float al0 = fmaxf(-g0, 1.0f + HEPS);
            float al1 = fmaxf(-g1, 1.0f + HEPS);
            float al2 = fmaxf(-g2, 1.0f + HEPS);
            float al3 = fmaxf(-g3, 1.0f + HEPS);
            float cc0 = w0 * acosh_coef(al0);
            float cc1 = w1 * acosh_coef(al1);
            float cc2 = w2 * acosh_coef(al2);
            float cc3 = w3 * acosh_coef(al3);
            float S = DOT5(cc0, cc1, cc2, cc3, 0.0f, al0, al1, al2, al3, 0.0f);

            float gm0 = fmaf(-S, b0v, cc0);
            float gm1 = fmaf(-S, b1v, cc1);
            float gm2 = fmaf(-S, b2v, cc2);
            float gm3 = fmaf(-S, b3v, cc3);
            float gm4 = -S * b4v;

            float Gg0, Gg1, Gg2, Gg3, Gg4;
            GMV(Gg0, Gg1, Gg2, Gg3, Gg4, gm0, gm1, gm2, gm3, gm4);
            float qq = DOT5(Gg0, Gg1, Gg2, Gg3, Gg4, gm0, gm1, gm2, gm3, gm4);

            float sq = fmaxf(0.25f * qq, 1e-12f);
            float nrm = sqrtf(sq);
            float ep = __expf(nrm), em = frcp(ep);
            float ch = 0.5f * (ep + em);
            float sc = 0.25f * (ep - em) * frcp(fmaxf(nrm, HEPS));

            b0v = fmaf(ch, b0v, sc * gm0);
            b1v = fmaf(ch, b1v, sc * gm1);
            b2v = fmaf(ch, b2v, sc * gm2);
            b3v = fmaf(ch, b3v, sc * gm3);
            b4v = fmaf(ch, b4v, sc * gm4);
            g0  = fmaf(ch, g0, sc * Gg0);
            g1  = fmaf(ch, g1, sc * Gg1);
            g2  = fmaf(ch, g2, sc * Gg2);
            g3  = fmaf(ch, g3, sc * Gg3);
            g4s = fmaf(ch, g4s, sc * Gg4);

            float xx = DOT5(g0, g1, g2, g3, g4s, b0v, b1v, b2v, b3v, b4v);
            float xt = DOT5(b0v, b1v, b2v, b3v, b4v, tau0, tau1, tau2, tau3, 1.0f);
            float tc = sqrtf(fmaf(xt, xt, 1.0f + xx));
            float dl = tc - xt;
            b4v += dl;
            g0 = fmaf(dl, nt0, g0); g1 = fmaf(dl, nt1, g1);
            g2 = fmaf(dl, nt2, g2); g3 = fmaf(dl, nt3, g3);
            g4s -= dl;
        }

        betas[tid][0] = b0v;
        betas[tid][1] = b1v;
        betas[tid][2] = b2v;
        betas[tid][3] = b3v;
        betas[tid][4] = b4v;
    }

    __syncthreads();

    // ---------------- phase 2c: reconstruction (quad layout) ---------------
    if (act) {
        float b0v = betas[il2][0];
        float b1v = betas[il2][1];
        float b2v = betas[il2][2];
        float b3v = betas[il2][3];
        float b4v = betas[il2][4];

        float r[8];
        #pragma unroll
        for (int j = 0; j < 8; ++j)
            r[j] = fmaf(b0v, hv[0][j], fmaf(b1v, hv[1][j],
                   fmaf(b2v, hv[2][j], b3v * hv[3][j])));
        if (sub == 0) r[0] += b4v;

        float4* po = reinterpret_cast<float4*>(
            out + (size_t)4 * osz + (size_t)item * DD + sub * 8);
        po[0] = make_float4(r[0], r[1], r[2], r[3]);
        po[1] = make_float4(r[4], r[5], r[6], r[7]);
    }
}

extern "C" void kernel_launch(void* const* d_in, const int* in_sizes, int n_in,
                              void* d_out, int out_size, void* d_ws, size_t ws_size,
                              hipStream_t stream)
{
    const float* x0 = (const float*)d_in[0];
    const float* x1 = (const float*)d_in[1];
    const float* x2 = (const float*)d_in[2];
    const float* x3 = (const float*)d_in[3];
    const float* W0 = (const float*)d_in[4];
    const float* b0 = (const float*)d_in[5];
    const float* W1 = (const float*)d_in[6];
    const float* b1 = (const float*)d_in[7];
    const float* W2 = (const float*)d_in[8];
    const float* b2 = (const float*)d_in[9];
    const float* W3 = (const float*)d_in[10];
    const float* b3 = (const float*)d_in[11];
    const float* es = (const float*)d_in[12];
    const float* lw = (const float*)d_in[13];

    const int n_items = in_sizes[0] / SEG;   // 262144
    prep_kernel<<<7, 256, 0, stream>>>(W0, b0, W1, b1, W2, b2, W3, b3,
                                       es, (unsigned*)d_ws);

    const int gx = (n_items + IPB - 1) / IPB;       // 4096
    fused_kernel<<<gx, 256, 0, stream>>>(x0, x1, x2, x3,
                                         (const unsigned*)d_ws, lw,
                                         (float*)d_out, n_items);
}

// Round 16
// 98.938 us; speedup vs baseline: 1.5966x; 1.0130x over previous
//
#include <hip/hip_runtime.h>

#define SEG 24
#define DD  32
#define HEPS 1e-7f
#define N_ITERS 10
#define IPB 64                         // items per block

typedef _Float16 h2 __attribute__((ext_vector_type(2)));
typedef __fp16   f16v2 __attribute__((ext_vector_type(2)));

__device__ __forceinline__ float frcp(float x) { return __builtin_amdgcn_rcpf(x); }

__device__ __forceinline__ float qx1(float x) {
    return __int_as_float(__builtin_amdgcn_mov_dpp(__float_as_int(x), 0xB1, 0xF, 0xF, true));
}
__device__ __forceinline__ float qx2(float x) {
    return __int_as_float(__builtin_amdgcn_mov_dpp(__float_as_int(x), 0x4E, 0xF, 0xF, true));
}
__device__ __forceinline__ float qsum(float x) {
    x += qx1(x);
    x += qx2(x);
    return x;
}

__device__ __forceinline__ float acosh_coef(float a) {
    float am = fmaf(a, a, -1.0f);
    float s  = sqrtf(am);
    return __logf(a + s) * frcp(s);
}

__device__ __forceinline__ float edot8(const float a[8], const float b[8]) {
    float x = fmaf(a[0], b[0], a[1] * b[1]);
    float y = fmaf(a[2], b[2], a[3] * b[3]);
    float z = fmaf(a[4], b[4], a[5] * b[5]);
    float w = fmaf(a[6], b[6], a[7] * b[7]);
    return qsum((x + y) + (z + w));
}

__device__ __forceinline__ unsigned pk_u32(float a, float b) {
    union { f16v2 f; unsigned u; } c;
    c.f = __builtin_amdgcn_cvt_pkrtz(a, b);
    return c.u;
}
__device__ __forceinline__ h2 pk_h2(float a, float b) {
    union { f16v2 f; h2 h; } c;
    c.f = __builtin_amdgcn_cvt_pkrtz(a, b);
    return c.h;
}
__device__ __forceinline__ h2 as_h2(unsigned u) {
    union { unsigned u; h2 h; } c; c.u = u; return c.h;
}

// ws layout (dwords): [0,1536) packed W f16x2 (s*384 + row*12 + j)
//                     [1536,1664) b f32 (s*32 + d) ; [1664] tanh(es)
#define WS_B_OFF 1536
#define WS_TS_OFF 1664

// ============ K0: pack W to f16x2, copy b, tanh(es) -> d_ws =================
__global__ __launch_bounds__(256)
void prep_kernel(const float* __restrict__ W0, const float* __restrict__ b0,
                 const float* __restrict__ W1, const float* __restrict__ b1,
                 const float* __restrict__ W2, const float* __restrict__ b2,
                 const float* __restrict__ W3, const float* __restrict__ b3,
                 const float* __restrict__ es, unsigned* __restrict__ ws)
{
    const int t = blockIdx.x * blockDim.x + threadIdx.x;
    const float* Ws[4] = { W0, W1, W2, W3 };
    const float* bs[4] = { b0, b1, b2, b3 };
    if (t < 1536) {
        int s = t / 384, rem = t % 384, r = rem / 12, j = rem % 12;
        float a = Ws[s][r * SEG + 2 * j];
        float b = Ws[s][r * SEG + 2 * j + 1];
        ws[t] = pk_u32(a, b);
    } else if (t < 1664) {
        int p = t - 1536;
        reinterpret_cast<float*>(ws)[WS_B_OFF + p] = bs[p / 32][p % 32];
    } else if (t == 1664) {
        reinterpret_cast<float*>(ws)[WS_TS_OFF] = tanhf(es[0]);
    }
}

// ============ K1: fused; gstate/betas aliased into the 32 KB h-LDS ==========
#define GMV(o0,o1,o2,o3,o4, v0,v1,v2,v3,v4)                                   \
    o0 = fmaf(G00,(v0), fmaf(G01,(v1), fmaf(G02,(v2), fmaf(G03,(v3), nt0*(v4))))); \
    o1 = fmaf(G01,(v0), fmaf(G11,(v1), fmaf(G12,(v2), fmaf(G13,(v3), nt1*(v4))))); \
    o2 = fmaf(G02,(v0), fmaf(G12,(v1), fmaf(G22,(v2), fmaf(G23,(v3), nt2*(v4))))); \
    o3 = fmaf(G03,(v0), fmaf(G13,(v1), fmaf(G23,(v2), fmaf(G33,(v3), nt3*(v4))))); \
    o4 = fmaf(nt0,(v0), fmaf(nt1,(v1), fmaf(nt2,(v2), fmaf(nt3,(v3), -(v4)))));

#define DOT5(a0,a1,a2,a3,a4, c0,c1,c2,c3,c4) \
    fmaf((a0),(c0), fmaf((a1),(c1), fmaf((a2),(c2), fmaf((a3),(c3), (a4)*(c4)))))

__global__ __launch_bounds__(256)
void fused_kernel(const float* __restrict__ x0, const float* __restrict__ x1,
                  const float* __restrict__ x2, const float* __restrict__ x3,
                  const unsigned* __restrict__ ws, const float* __restrict__ lw,
                  float* __restrict__ out, int n_items)
{
    // 32 KB total. lds4 spans all of it (h hand-off). gstate/betas alias the
    // front — they are only WRITTEN after the last lds4 READ (hv is held in
    // registers from phase 2a onward; phase 1.5 completes before B2).
    __shared__ __align__(16) unsigned char smem[4 * IPB * 8 * 16];
    float4* lds4 = reinterpret_cast<float4*>(smem);
    float (*gstate)[20] = reinterpret_cast<float (*)[20]>(smem);
    float (*betas)[5]   = reinterpret_cast<float (*)[5]>(smem + IPB * 20 * 4);

    const int tid   = threadIdx.x;
    const int item0 = blockIdx.x * IPB;
    const size_t osz = (size_t)n_items * DD;

    const float* wsf = reinterpret_cast<const float*>(ws);
    const float  ts  = wsf[WS_TS_OFF];

    // ---------------- phase 1: encode one (item, stream) per thread --------
    {
        const int s1  = tid >> 6;                    // wave-uniform stream id
        const int il1 = tid & 63;
        const int it1 = item0 + il1;

        const float* xp;
        if      (s1 == 0) xp = x0;
        else if (s1 == 1) xp = x1;
        else if (s1 == 2) xp = x2;
        else              xp = x3;

        const unsigned* W2p = ws + (size_t)s1 * 384; // s_load source
        const float*    B2p = wsf + WS_B_OFF + s1 * 32;

        if (it1 < n_items) {
            float seg[SEG];
            const float4* sp = reinterpret_cast<const float4*>(xp + (size_t)it1 * SEG);
            #pragma unroll
            for (int j = 0; j < SEG / 4; ++j) {
                float4 v = sp[j];
                seg[4*j+0] = v.x; seg[4*j+1] = v.y; seg[4*j+2] = v.z; seg[4*j+3] = v.w;
            }
            h2 sp2[SEG / 2];
            #pragma unroll
            for (int j = 0; j < SEG / 2; ++j)
                sp2[j] = pk_h2(seg[2*j], seg[2*j+1]);

            float u[DD];
            #pragma unroll
            for (int d = 0; d < DD; ++d) {
                float z = B2p[d];                    // wave-uniform -> s_load
                #pragma unroll
                for (int j = 0; j < SEG / 2; ++j)
                    z = __builtin_amdgcn_fdot2(sp2[j], as_h2(W2p[d * 12 + j]), z, false);
                u[d] = z * ts;
            }

            float q0 = 0.f, q1 = 0.f, q2 = 0.f, q3 = 0.f;
            #pragma unroll
            for (int d = 0; d < DD; d += 4) {
                q0 = fmaf(u[d+0], u[d+0], q0);
                q1 = fmaf(u[d+1], u[d+1], q1);
                q2 = fmaf(u[d+2], u[d+2], q2);
                q3 = fmaf(u[d+3], u[d+3], q3);
            }
            float sq = (q0 + q1) + (q2 + q3) - 2.0f * u[0] * u[0];
            sq = fmaxf(sq, 1e-12f);
            float nrm = sqrtf(sq);
            float ep = __expf(nrm), em = frcp(ep);
            float sh = 0.5f * (ep - em);
            float sc = sh * frcp(fmaxf(nrm, HEPS));

            float r0 = 0.f, r1 = 0.f, r2 = 0.f, r3 = 0.f;
            #pragma unroll
            for (int d = 1; d < DD; ++d) {
                float yv = sc * u[d];
                u[d] = yv;
                if ((d & 3) == 0) r0 = fmaf(yv, yv, r0);
                else if ((d & 3) == 1) r1 = fmaf(yv, yv, r1);
                else if ((d & 3) == 2) r2 = fmaf(yv, yv, r2);
                else r3 = fmaf(yv, yv, r3);
            }
            u[0] = sqrtf(1.0f + (r0 + r1) + (r2 + r3));  // projx time component

            // swizzled LDS write (f32, no conversion)
            #pragma unroll
            for (int j = 0; j < DD / 4; ++j) {
                int slot = (s1 * IPB + il1) * 8 + (j ^ (il1 & 7));
                lds4[slot] = make_float4(u[4*j+0], u[4*j+1], u[4*j+2], u[4*j+3]);
            }
        }
    }

    __syncthreads();                                 // B1: lds4 h complete

    // ---------------- phase 1.5: cooperative dense h store -----------------
    #pragma unroll
    for (int c = 0; c < 8; ++c) {
        int f   = c * 256 + tid;                     // 0..2047
        int s   = f >> 9;                            // uniform per (c, wave)
        int rem = f & 511;                           // float4 idx in stream chunk
        int it  = rem >> 3;
        int j   = rem & 7;
        if (item0 + it < n_items) {
            int slot = (s * IPB + it) * 8 + (j ^ (it & 7));
            reinterpret_cast<float4*>(out + (size_t)s * osz + (size_t)item0 * DD)[rem]
                = lds4[slot];
        }
    }

    // ---------------- phase 2a: quad-layout hv load + Gram (to registers) --
    const int il2  = tid >> 2;
    const int sub  = tid & 3;
    const int item = item0 + il2;
    const bool act = (item < n_items);

    float hv[4][8];
    float Ga0=0,Ga1=0,Ga2=0,Ga3=0, Gb0=0,Gb1=0,Gb2=0,Gb3=0, Gc0=0,Gc1=0;
    float tau0r=0, tau1r=0, tau2r=0, tau3r=0;

    if (act) {
        #pragma unroll
        for (int s = 0; s < 4; ++s) {
            float4 a = lds4[(s * IPB + il2) * 8 + ((2*sub)     ^ (il2 & 7))];
            float4 b = lds4[(s * IPB + il2) * 8 + ((2*sub + 1) ^ (il2 & 7))];
            hv[s][0] = a.x; hv[s][1] = a.y; hv[s][2] = a.z; hv[s][3] = a.w;
            hv[s][4] = b.x; hv[s][5] = b.y; hv[s][6] = b.z; hv[s][7] = b.w;
        }

        const float is0 = (sub == 0) ? 1.0f : 0.0f;
        tau0r = qsum(is0 * hv[0][0]);
        tau1r = qsum(is0 * hv[1][0]);
        tau2r = qsum(is0 * hv[2][0]);
        tau3r = qsum(is0 * hv[3][0]);

        float d00 = edot8(hv[0], hv[0]);
        float d01 = edot8(hv[0], hv[1]);
        float d02 = edot8(hv[0], hv[2]);
        float d03 = edot8(hv[0], hv[3]);
        float d11 = edot8(hv[1], hv[1]);
        float d12 = edot8(hv[1], hv[2]);
        float d13 = edot8(hv[1], hv[3]);
        float d22 = edot8(hv[2], hv[2]);
        float d23 = edot8(hv[2], hv[3]);
        float d33 = edot8(hv[3], hv[3]);

        Ga0 = fmaf(-2.0f*tau0r, tau0r, d00);
        Ga1 = fmaf(-2.0f*tau0r, tau1r, d01);
        Ga2 = fmaf(-2.0f*tau0r, tau2r, d02);
        Ga3 = fmaf(-2.0f*tau0r, tau3r, d03);
        Gb0 = fmaf(-2.0f*tau1r, tau1r, d11);
        Gb1 = fmaf(-2.0f*tau1r, tau2r, d12);
        Gb2 = fmaf(-2.0f*tau1r, tau3r, d13);
        Gb3 = fmaf(-2.0f*tau2r, tau2r, d22);
        Gc0 = fmaf(-2.0f*tau2r, tau3r, d23);
        Gc1 = fmaf(-2.0f*tau3r, tau3r, d33);
    }

    __syncthreads();                // B2: ALL lds4 reads done -> safe to alias

    if (act && sub == 0) {
        float4* g4 = reinterpret_cast<float4*>(gstate[il2]);
        g4[0] = make_float4(Ga0, Ga1, Ga2, Ga3);
        g4[1] = make_float4(Gb0, Gb1, Gb2, Gb3);
        g4[2] = make_float4(Gc0, Gc1, tau0r, tau1r);
        g4[3] = make_float4(tau2r, tau3r, 0.0f, 0.0f);
    }

    __syncthreads();                                 // B3: gstate visible

    // ---------------- phase 2b: 5-d Frechet, ONE lane per item -------------
    if (tid < IPB && (item0 + tid) < n_items) {
        float l0 = lw[0], l1 = lw[1], l2w = lw[2], l3 = lw[3];
        float mxw = fmaxf(fmaxf(l0, l1), fmaxf(l2w, l3));
        float e0 = __expf(l0 - mxw), e1 = __expf(l1 - mxw),
              e2 = __expf(l2w - mxw), e3 = __expf(l3 - mxw);
        float winv = frcp(e0 + e1 + e2 + e3);
        float w0 = e0 * winv, w1 = e1 * winv, w2 = e2 * winv, w3 = e3 * winv;

        const float4* g4 = reinterpret_cast<const float4*>(gstate[tid]);
        float4 ga = g4[0], gb = g4[1], gc = g4[2], gd = g4[3];
        float G00 = ga.x, G01 = ga.y, G02 = ga.z, G03 = ga.w;
        float G11 = gb.x, G12 = gb.y, G13 = gb.z, G22 = gb.w;
        float G23 = gc.x, G33 = gc.y;
        float tau0 = gc.z, tau1 = gc.w, tau2 = gd.x, tau3 = gd.y;
        float nt0 = -tau0, nt1 = -tau1, nt2 = -tau2, nt3 = -tau3;

        float b0v, b1v, b2v, b3v, b4v, g0, g1, g2, g3, g4s;
        {
            float al0 = fmaxf(tau0, 1.0f + HEPS);
            float al1 = fmaxf(tau1, 1.0f + HEPS);
            float al2 = fmaxf(tau2, 1.0f + HEPS);
            float al3 = fmaxf(tau3, 1.0f + HEPS);
            float cc0 = w0 * acosh_coef(al0);
            float cc1 = w1 * acosh_coef(al1);
            float cc2 = w2 * acosh_coef(al2);
            float cc3 = w3 * acosh_coef(al3);
            b0v = cc0; b1v = cc1; b2v = cc2; b3v = cc3;
            b4v = -DOT5(cc0, cc1, cc2, cc3, 0.0f, al0, al1, al2, al3, 0.0f);

            GMV(g0, g1, g2, g3, g4s, b0v, b1v, b2v, b3v, b4v);
            float gq = DOT5(g0, g1, g2, g3, g4s, b0v, b1v, b2v, b3v, b4v);
            float sq = fmaxf(gq, 1e-12f);
            float nrm = sqrtf(sq);
            float ep = __expf(nrm), em = frcp(ep);
            float ch = 0.5f * (ep + em);
            float sc = 0.5f * (ep - em) * frcp(fmaxf(nrm, HEPS));
            b0v *= sc; b1v *= sc; b2v *= sc; b3v *= sc;
            b4v = fmaf(sc, b4v, ch);

            GMV(g0, g1, g2, g3, g4s, b0v, b1v, b2v, b3v, b4v);
            float xx = DOT5(g0, g1, g2, g3, g4s, b0v, b1v, b2v, b3v, b4v);
            float xt = DOT5(b0v, b1v, b2v, b3v, b4v, tau0, tau1, tau2, tau3, 1.0f);
            float tc = sqrtf(fmaf(xt, xt, 1.0f + xx));
            float dl = tc - xt;
            b4v += dl;
            g0 = fmaf(dl, nt0, g0); g1 = fmaf(dl, nt1, g1);
            g2 = fmaf(dl, nt2, g2); g3 = fmaf(dl, nt3, g3);
            g4s -= dl;
        }

        for (int it = 0; it < N_ITERS; ++it) {
            float al0 = fmaxf(-g0, 1.0f + HEPS);
            float al1 = fmaxf(-g1, 1.0f + HEPS);
            float al2 = fmaxf(-g2, 1.0f + HEPS);
            float al3 = fmaxf(-g3, 1.0f + HEPS);
            float cc0 = w0 * acosh_coef(al0);
            float cc1 = w1 * acosh_coef(al1);
            float cc2 = w2 * acosh_coef(al2);
            float cc3 = w3 * acosh_coef(al3);
            float S = DOT5(cc0, cc1, cc2, cc3, 0.0f, al0, al1, al2, al3, 0.0f);

            float gm0 = fmaf(-S, b0v, cc0);
            float gm1 = fmaf(-S, b1v, cc1);
            float gm2 = fmaf(-S, b2v, cc2);
            float gm3 = fmaf(-S, b3v, cc3);
            float gm4 = -S * b4v;

            float Gg0, Gg1, Gg2, Gg3, Gg4;
            GMV(Gg0, Gg1, Gg2, Gg3, Gg4, gm0, gm1, gm2, gm3, gm4);
            float qq = DOT5(Gg0, Gg1, Gg2, Gg3, Gg4, gm0, gm1, gm2, gm3, gm4);

            float sq = fmaxf(0.25f * qq, 1e-12f);
            float nrm = sqrtf(sq);
            float ep = __expf(nrm), em = frcp(ep);
            float ch = 0.5f * (ep + em);
            float sc = 0.25f * (ep - em) * frcp(fmaxf(nrm, HEPS));

            b0v = fmaf(ch, b0v, sc * gm0);
            b1v = fmaf(ch, b1v, sc * gm1);
            b2v = fmaf(ch, b2v, sc * gm2);
            b3v = fmaf(ch, b3v, sc * gm3);
            b4v = fmaf(ch, b4v, sc * gm4);
            g0  = fmaf(ch, g0, sc * Gg0);
            g1  = fmaf(ch, g1, sc * Gg1);
            g2  = fmaf(ch, g2, sc * Gg2);
            g3  = fmaf(ch, g3, sc * Gg3);
            g4s = fmaf(ch, g4s, sc * Gg4);

            float xx = DOT5(g0, g1, g2, g3, g4s, b0v, b1v, b2v, b3v, b4v);
            float xt = DOT5(b0v, b1v, b2v, b3v, b4v, tau0, tau1, tau2, tau3, 1.0f);
            float tc = sqrtf(fmaf(xt, xt, 1.0f + xx));
            float dl = tc - xt;
            b4v += dl;
            g0 = fmaf(dl, nt0, g0); g1 = fmaf(dl, nt1, g1);
            g2 = fmaf(dl, nt2, g2); g3 = fmaf(dl, nt3, g3);
            g4s -= dl;
        }

        betas[tid][0] = b0v;
        betas[tid][1] = b1v;
        betas[tid][2] = b2v;
        betas[tid][3] = b3v;
        betas[tid][4] = b4v;
    }

    __syncthreads();                                 // B4: betas visible

    // ---------------- phase 2c: reconstruction (quad layout) ---------------
    if (act) {
        float b0v = betas[il2][0];
        float b1v = betas[il2][1];
        float b2v = betas[il2][2];
        float b3v = betas[il2][3];
        float b4v = betas[il2][4];

        float r[8];
        #pragma unroll
        for (int j = 0; j < 8; ++j)
            r[j] = fmaf(b0v, hv[0][j], fmaf(b1v, hv[1][j],
                   fmaf(b2v, hv[2][j], b3v * hv[3][j])));
        if (sub == 0) r[0] += b4v;

        float4* po = reinterpret_cast<float4*>(
            out + (size_t)4 * osz + (size_t)item * DD + sub * 8);
        po[0] = make_float4(r[0], r[1], r[2], r[3]);
        po[1] = make_float4(r[4], r[5], r[6], r[7]);
    }
}

extern "C" void kernel_launch(void* const* d_in, const int* in_sizes, int n_in,
                              void* d_out, int out_size, void* d_ws, size_t ws_size,
                              hipStream_t stream)
{
    const float* x0 = (const float*)d_in[0];
    const float* x1 = (const float*)d_in[1];
    const float* x2 = (const float*)d_in[2];
    const float* x3 = (const float*)d_in[3];
    const float* W0 = (const float*)d_in[4];
    const float* b0 = (const float*)d_in[5];
    const float* W1 = (const float*)d_in[6];
    const float* b1 = (const float*)d_in[7];
    const float* W2 = (const float*)d_in[8];
    const float* b2 = (const float*)d_in[9];
    const float* W3 = (const float*)d_in[10];
    const float* b3 = (const float*)d_in[11];
    const float* es = (const float*)d_in[12];
    const float* lw = (const float*)d_in[13];

    const int n_items = in_sizes[0] / SEG;   // 262144
    prep_kernel<<<7, 256, 0, stream>>>(W0, b0, W1, b1, W2, b2, W3, b3,
                                       es, (unsigned*)d_ws);

    const int gx = (n_items + IPB - 1) / IPB;       // 4096
    fused_kernel<<<gx, 256, 0, stream>>>(x0, x1, x2, x3,
                                         (const unsigned*)d_ws, lw,
                                         (float*)d_out, n_items);
}

// Round 18
// 78.147 us; speedup vs baseline: 2.0214x; 1.2661x over previous
//
#include <hip/hip_runtime.h>

#define SEG 24
#define DD  32
#define HEPS 1e-7f
#define N_ITERS 10
#define IPB 64                         // items per block

typedef _Float16 h2    __attribute__((ext_vector_type(2)));
typedef _Float16 half8 __attribute__((ext_vector_type(8)));
typedef float    f32x4 __attribute__((ext_vector_type(4)));

__device__ __forceinline__ float frcp(float x) { return __builtin_amdgcn_rcpf(x); }

__device__ __forceinline__ float qx1(float x) {
    return __int_as_float(__builtin_amdgcn_mov_dpp(__float_as_int(x), 0xB1, 0xF, 0xF, true));
}
__device__ __forceinline__ float qx2(float x) {
    return __int_as_float(__builtin_amdgcn_mov_dpp(__float_as_int(x), 0x4E, 0xF, 0xF, true));
}
__device__ __forceinline__ float qsum(float x) {
    x += qx1(x);
    x += qx2(x);
    return x;
}

__device__ __forceinline__ float acosh_coef(float a) {
    float am = fmaf(a, a, -1.0f);
    float s  = sqrtf(am);
    return __logf(a + s) * frcp(s);
}

__device__ __forceinline__ float edot8(const float a[8], const float b[8]) {
    float x = fmaf(a[0], b[0], a[1] * b[1]);
    float y = fmaf(a[2], b[2], a[3] * b[3]);
    float z = fmaf(a[4], b[4], a[5] * b[5]);
    float w = fmaf(a[6], b[6], a[7] * b[7]);
    return qsum((x + y) + (z + w));
}

// round-to-nearest-even f16 packing (cvt_pkrtz is round-toward-zero: biased)
__device__ __forceinline__ unsigned pk_rne_u32(float a, float b) {
    union { _Float16 h[2]; unsigned u; } c;
    c.h[0] = (_Float16)a;
    c.h[1] = (_Float16)b;
    return c.u;
}
__device__ __forceinline__ h2 pk_rne_h2(float a, float b) {
    h2 r;
    r[0] = (_Float16)a;
    r[1] = (_Float16)b;
    return r;
}

// ws layout (dwords):
//   [0,2048)    B-fragments f16x2, ts-folded:  idx = ((s*2+nt)*64 + lane)*4 + q
//               element q covers k0=(lane>>4)*8+2q, n = nt*16+(lane&15); k>=24 -> 0
//   [2048,2176) b' = b*ts  f32  (s*32 + d)
#define WS_BP_OFF 2048

// ============ K0: pack B fragments (W^T * ts) + b*ts -> d_ws ================
__global__ __launch_bounds__(256)
void prep_kernel(const float* __restrict__ W0, const float* __restrict__ b0,
                 const float* __restrict__ W1, const float* __restrict__ b1,
                 const float* __restrict__ W2, const float* __restrict__ b2,
                 const float* __restrict__ W3, const float* __restrict__ b3,
                 const float* __restrict__ es, unsigned* __restrict__ ws)
{
    const int t = blockIdx.x * blockDim.x + threadIdx.x;
    const float* Ws[4] = { W0, W1, W2, W3 };
    const float* bs[4] = { b0, b1, b2, b3 };
    const float ts = tanhf(es[0]);
    if (t < 2048) {
        int s    = t >> 9;
        int rem  = t & 511;
        int nt   = rem >> 8;
        int lane = (rem >> 2) & 63;
        int q    = rem & 3;
        int n    = nt * 16 + (lane & 15);
        int k0   = (lane >> 4) * 8 + 2 * q;
        const float* W = Ws[s];
        float a = (k0     < SEG) ? W[n * SEG + k0]     * ts : 0.0f;
        float c = (k0 + 1 < SEG) ? W[n * SEG + k0 + 1] * ts : 0.0f;
        ws[t] = pk_rne_u32(a, c);
    } else if (t < 2176) {
        int p = t - 2048;
        reinterpret_cast<float*>(ws)[WS_BP_OFF + p] = bs[p / 32][p % 32] * ts;
    }
}

// ============ K1: fused; MFMA encode + LDS hand-off + 5-d Frechet ===========
#define GMV(o0,o1,o2,o3,o4, v0,v1,v2,v3,v4)                                   \
    o0 = fmaf(G00,(v0), fmaf(G01,(v1), fmaf(G02,(v2), fmaf(G03,(v3), nt0*(v4))))); \
    o1 = fmaf(G01,(v0), fmaf(G11,(v1), fmaf(G12,(v2), fmaf(G13,(v3), nt1*(v4))))); \
    o2 = fmaf(G02,(v0), fmaf(G12,(v1), fmaf(G22,(v2), fmaf(G23,(v3), nt2*(v4))))); \
    o3 = fmaf(G03,(v0), fmaf(G13,(v1), fmaf(G23,(v2), fmaf(G33,(v3), nt3*(v4))))); \
    o4 = fmaf(nt0,(v0), fmaf(nt1,(v1), fmaf(nt2,(v2), fmaf(nt3,(v3), -(v4)))));

#define DOT5(a0,a1,a2,a3,a4, c0,c1,c2,c3,c4) \
    fmaf((a0),(c0), fmaf((a1),(c1), fmaf((a2),(c2), fmaf((a3),(c3), (a4)*(c4)))))

__global__ __launch_bounds__(256)
void fused_kernel(const float* __restrict__ x0, const float* __restrict__ x1,
                  const float* __restrict__ x2, const float* __restrict__ x3,
                  const unsigned* __restrict__ ws, const float* __restrict__ lw,
                  float* __restrict__ out, int n_items)
{
    __shared__ __align__(16) unsigned char smem[4 * IPB * 8 * 16];   // 32 KB
    float4* lds4 = reinterpret_cast<float4*>(smem);
    float*  ldsf = reinterpret_cast<float*>(smem);
    float (*gstate)[20] = reinterpret_cast<float (*)[20]>(smem);
    float (*betas)[5]   = reinterpret_cast<float (*)[5]>(smem + IPB * 20 * 4);

    const int tid   = threadIdx.x;
    const int item0 = blockIdx.x * IPB;
    const size_t osz = (size_t)n_items * DD;

    const float* wsf = reinterpret_cast<const float*>(ws);

    // ---------------- phase 1: MFMA encode, one stream per wave ------------
    {
        const int w    = tid >> 6;                   // wave id = stream id
        const int lane = tid & 63;
        const int g    = lane >> 4;
        const int lm   = lane & 15;

        const float* xp;
        if      (w == 0) xp = x0;
        else if (w == 1) xp = x1;
        else if (w == 2) xp = x2;
        else             xp = x3;

        // B fragments (ts-folded) and b' accumulator inits
        union { uint4 u; half8 v; } Bf0, Bf1;
        Bf0.u = reinterpret_cast<const uint4*>(ws)[(w * 2 + 0) * 64 + lane];
        Bf1.u = reinterpret_cast<const uint4*>(ws)[(w * 2 + 1) * 64 + lane];
        const float bv0 = wsf[WS_BP_OFF + w * 32 + lm];
        const float bv1 = wsf[WS_BP_OFF + w * 32 + 16 + lm];
        const f32x4 init0 = { bv0, bv0, bv0, bv0 };
        const f32x4 init1 = { bv1, bv1, bv1, bv1 };

        f32x4 acc[4][2];
        #pragma unroll
        for (int m = 0; m < 4; ++m) {
            union { h2 h[4]; half8 v; } A;
            A.h[0] = pk_rne_h2(0.f, 0.f); A.h[1] = pk_rne_h2(0.f, 0.f);
            A.h[2] = pk_rne_h2(0.f, 0.f); A.h[3] = pk_rne_h2(0.f, 0.f);
            int item = item0 + m * 16 + lm;
            if (g < 3 && item < n_items) {
                const float4* ap = reinterpret_cast<const float4*>(
                    xp + (size_t)item * SEG + g * 8);
                float4 a0 = ap[0], a1 = ap[1];
                A.h[0] = pk_rne_h2(a0.x, a0.y);
                A.h[1] = pk_rne_h2(a0.z, a0.w);
                A.h[2] = pk_rne_h2(a1.x, a1.y);
                A.h[3] = pk_rne_h2(a1.z, a1.w);
            }
            acc[m][0] = __builtin_amdgcn_mfma_f32_16x16x32_f16(A.v, Bf0.v, init0, 0, 0, 0);
            acc[m][1] = __builtin_amdgcn_mfma_f32_16x16x32_f16(A.v, Bf1.v, init1, 0, 0, 0);
        }

        // scatter u = acc into the swizzled LDS h-layout
        #pragma unroll
        for (int r = 0; r < 4; ++r) {
            int i7   = (g * 4 + r) & 7;
            int it_b = w * IPB + g * 4 + r;          // + m*16 via m*512 floats
            int s0 = (it_b * 8 + ((lm >> 2)       ^ i7)) * 4 + (lm & 3);
            int s1 = (it_b * 8 + ((4 + (lm >> 2)) ^ i7)) * 4 + (lm & 3);
            #pragma unroll
            for (int m = 0; m < 4; ++m) {
                ldsf[s0 + m * 512] = acc[m][0][r];
                ldsf[s1 + m * 512] = acc[m][1][r];
            }
        }
    }

    // ---------------- phase 1b: per-thread nonlinear (same wave) -----------
    {
        const int s1  = tid >> 6;
        const int il1 = tid & 63;
        const int it1 = item0 + il1;

        if (it1 < n_items) {
            float u[DD];
            #pragma unroll
            for (int j = 0; j < DD / 4; ++j) {
                float4 v = lds4[(s1 * IPB + il1) * 8 + (j ^ (il1 & 7))];
                u[4*j+0] = v.x; u[4*j+1] = v.y; u[4*j+2] = v.z; u[4*j+3] = v.w;
            }

            float q0 = 0.f, q1 = 0.f, q2 = 0.f, q3 = 0.f;
            #pragma unroll
            for (int d = 0; d < DD; d += 4) {
                q0 = fmaf(u[d+0], u[d+0], q0);
                q1 = fmaf(u[d+1], u[d+1], q1);
                q2 = fmaf(u[d+2], u[d+2], q2);
                q3 = fmaf(u[d+3], u[d+3], q3);
            }
            float sq = (q0 + q1) + (q2 + q3) - 2.0f * u[0] * u[0];
            sq = fmaxf(sq, 1e-12f);
            float nrm = sqrtf(sq);
            float ep = __expf(nrm), em = frcp(ep);
            float sh = 0.5f * (ep - em);
            float sc = sh * frcp(fmaxf(nrm, HEPS));

            float r0 = 0.f, r1 = 0.f, r2 = 0.f, r3 = 0.f;
            #pragma unroll
            for (int d = 1; d < DD; ++d) {
                float yv = sc * u[d];
                u[d] = yv;
                if ((d & 3) == 0) r0 = fmaf(yv, yv, r0);
                else if ((d & 3) == 1) r1 = fmaf(yv, yv, r1);
                else if ((d & 3) == 2) r2 = fmaf(yv, yv, r2);
                else r3 = fmaf(yv, yv, r3);
            }
            u[0] = sqrtf(1.0f + (r0 + r1) + (r2 + r3));      // projx time comp

            #pragma unroll
            for (int j = 0; j < DD / 4; ++j) {
                int slot = (s1 * IPB + il1) * 8 + (j ^ (il1 & 7));
                lds4[slot] = make_float4(u[4*j+0], u[4*j+1], u[4*j+2], u[4*j+3]);
            }
        }
    }

    __syncthreads();                                 // B1: lds4 h complete

    // ---------------- phase 1.5: cooperative dense h store -----------------
    #pragma unroll
    for (int c = 0; c < 8; ++c) {
        int f   = c * 256 + tid;
        int s   = f >> 9;
        int rem = f & 511;
        int it  = rem >> 3;
        int j   = rem & 7;
        if (item0 + it < n_items) {
            int slot = (s * IPB + it) * 8 + (j ^ (it & 7));
            reinterpret_cast<float4*>(out + (size_t)s * osz + (size_t)item0 * DD)[rem]
                = lds4[slot];
        }
    }

    // ---------------- phase 2a: quad-layout hv load + Gram (to registers) --
    const int il2  = tid >> 2;
    const int sub  = tid & 3;
    const int item = item0 + il2;
    const bool act = (item < n_items);

    float hv[4][8];
    float Ga1=0,Ga2=0,Ga3=0, Gb1=0,Gb2=0, Gc0=0;
    float tau0r=0, tau1r=0, tau2r=0, tau3r=0;

    if (act) {
        #pragma unroll
        for (int s = 0; s < 4; ++s) {
            float4 a = lds4[(s * IPB + il2) * 8 + ((2*sub)     ^ (il2 & 7))];
            float4 b = lds4[(s * IPB + il2) * 8 + ((2*sub + 1) ^ (il2 & 7))];
            hv[s][0] = a.x; hv[s][1] = a.y; hv[s][2] = a.z; hv[s][3] = a.w;
            hv[s][4] = b.x; hv[s][5] = b.y; hv[s][6] = b.z; hv[s][7] = b.w;
        }

        const float is0 = (sub == 0) ? 1.0f : 0.0f;
        tau0r = qsum(is0 * hv[0][0]);
        tau1r = qsum(is0 * hv[1][0]);
        tau2r = qsum(is0 * hv[2][0]);
        tau3r = qsum(is0 * hv[3][0]);

        // only the 6 cross dots are needed (diagonal is exactly -1 on the
        // hyperboloid: <h,h>_L = -1 after projx — avoids cancellation)
        float d01 = edot8(hv[0], hv[1]);
        float d02 = edot8(hv[0], hv[2]);
        float d03 = edot8(hv[0], hv[3]);
        float d12 = edot8(hv[1], hv[2]);
        float d13 = edot8(hv[1], hv[3]);
        float d23 = edot8(hv[2], hv[3]);

        Ga1 = fmaf(-2.0f*tau0r, tau1r, d01);
        Ga2 = fmaf(-2.0f*tau0r, tau2r, d02);
        Ga3 = fmaf(-2.0f*tau0r, tau3r, d03);
        Gb1 = fmaf(-2.0f*tau1r, tau2r, d12);
        Gb2 = fmaf(-2.0f*tau1r, tau3r, d13);
        Gc0 = fmaf(-2.0f*tau2r, tau3r, d23);
    }

    __syncthreads();                // B2: all lds4 reads done -> safe to alias

    if (act && sub == 0) {
        float4* g4 = reinterpret_cast<float4*>(gstate[il2]);
        g4[0] = make_float4(Ga1, Ga2, Ga3, Gb1);
        g4[1] = make_float4(Gb2, Gc0, tau0r, tau1r);
        g4[2] = make_float4(tau2r, tau3r, 0.0f, 0.0f);
    }

    __syncthreads();                                 // B3: gstate visible

    // ---------------- phase 2b: 5-d Frechet, ONE lane per item -------------
    if (tid < IPB && (item0 + tid) < n_items) {
        float l0 = lw[0], l1 = lw[1], l2w = lw[2], l3 = lw[3];
        float mxw = fmaxf(fmaxf(l0, l1), fmaxf(l2w, l3));
        float e0 = __expf(l0 - mxw), e1 = __expf(l1 - mxw),
              e2 = __expf(l2w - mxw), e3 = __expf(l3 - mxw);
        float winv = frcp(e0 + e1 + e2 + e3);
        float w0 = e0 * winv, w1 = e1 * winv, w2 = e2 * winv, w3 = e3 * winv;

        const float4* g4 = reinterpret_cast<const float4*>(gstate[tid]);
        float4 ga = g4[0], gb = g4[1], gc = g4[2];
        const float G00 = -1.0f, G11 = -1.0f, G22 = -1.0f, G33 = -1.0f;
        float G01 = ga.x, G02 = ga.y, G03 = ga.z, G12 = ga.w;
        float G13 = gb.x, G23 = gb.y;
        float tau0 = gb.z, tau1 = gb.w, tau2 = gc.x, tau3 = gc.y;
        float nt0 = -tau0, nt1 = -tau1, nt2 = -tau2, nt3 = -tau3;

        float b0v, b1v, b2v, b3v, b4v, g0, g1, g2, g3, g4s;
        {
            float al0 = fmaxf(tau0, 1.0f + HEPS);
            float al1 = fmaxf(tau1, 1.0f + HEPS);
            float al2 = fmaxf(tau2, 1.0f + HEPS);
            float al3 = fmaxf(tau3, 1.0f + HEPS);
            float cc0 = w0 * acosh_coef(al0);
            float cc1 = w1 * acosh_coef(al1);
            float cc2 = w2 * acosh_coef(al2);
            float cc3 = w3 * acosh_coef(al3);
            b0v = cc0; b1v = cc1; b2v = cc2; b3v = cc3;
            b4v = -DOT5(cc0, cc1, cc2, cc3, 0.0f, al0, al1, al2, al3, 0.0f);

            GMV(g0, g1, g2, g3, g4s, b0v, b1v, b2v, b3v, b4v);
            float gq = DOT5(g0, g1, g2, g3, g4s, b0v, b1v, b2v, b3v, b4v);
            float sq = fmaxf(gq, 1e-12f);
            float nrm = sqrtf(sq);
            float ep = __expf(nrm), em = frcp(ep);
            float ch = 0.5f * (ep + em);
            float sc = 0.5f * (ep - em) * frcp(fmaxf(nrm, HEPS));
            b0v *= sc; b1v *= sc; b2v *= sc; b3v *= sc;
            b4v = fmaf(sc, b4v, ch);

            GMV(g0, g1, g2, g3, g4s, b0v, b1v, b2v, b3v, b4v);
            float xx = DOT5(g0, g1, g2, g3, g4s, b0v, b1v, b2v, b3v, b4v);
            float xt = DOT5(b0v, b1v, b2v, b3v, b4v, tau0, tau1, tau2, tau3, 1.0f);
            float tc = sqrtf(fmaf(xt, xt, 1.0f + xx));
            float dl = tc - xt;
            b4v += dl;
            g0 = fmaf(dl, nt0, g0); g1 = fmaf(dl, nt1, g1);
            g2 = fmaf(dl, nt2, g2); g3 = fmaf(dl, nt3, g3);
            g4s -= dl;
        }

        for (int it = 0; it < N_ITERS; ++it) {
            float al0 = fmaxf(-g0, 1.0f + HEPS);
            float al1 = fmaxf(-g1, 1.0f + HEPS);
            float al2 = fmaxf(-g2, 1.0f + HEPS);
            float al3 = fmaxf(-g3, 1.0f + HEPS);
            float cc0 = w0 * acosh_coef(al0);
            float cc1 = w1 * acosh_coef(al1);
            float cc2 = w2 * acosh_coef(al2);
            float cc3 = w3 * acosh_coef(al3);
            float S = DOT5(cc0, cc1, cc2, cc3, 0.0f, al0, al1, al2, al3, 0.0f);

            float gm0 = fmaf(-S, b0v, cc0);
            float gm1 = fmaf(-S, b1v, cc1);
            float gm2 = fmaf(-S, b2v, cc2);
            float gm3 = fmaf(-S, b3v, cc3);
            float gm4 = -S * b4v;

            float Gg0, Gg1, Gg2, Gg3, Gg4;
            GMV(Gg0, Gg1, Gg2, Gg3, Gg4, gm0, gm1, gm2, gm3, gm4);
            float qq = DOT5(Gg0, Gg1, Gg2, Gg3, Gg4, gm0, gm1, gm2, gm3, gm4);

            float sq = fmaxf(0.25f * qq, 1e-12f);
            float nrm = sqrtf(sq);
            float ep = __expf(nrm), em = frcp(ep);
            float ch = 0.5f * (ep + em);
            float sc = 0.25f * (ep - em) * frcp(fmaxf(nrm, HEPS));

            b0v = fmaf(ch, b0v, sc * gm0);
            b1v = fmaf(ch, b1v, sc * gm1);
            b2v = fmaf(ch, b2v, sc * gm2);
            b3v = fmaf(ch, b3v, sc * gm3);
            b4v = fmaf(ch, b4v, sc * gm4);
            g0  = fmaf(ch, g0, sc * Gg0);
            g1  = fmaf(ch, g1, sc * Gg1);
            g2  = fmaf(ch, g2, sc * Gg2);
            g3  = fmaf(ch, g3, sc * Gg3);
            g4s = fmaf(ch, g4s, sc * Gg4);

            float xx = DOT5(g0, g1, g2, g3, g4s, b0v, b1v, b2v, b3v, b4v);
            float xt = DOT5(b0v, b1v, b2v, b3v, b4v, tau0, tau1, tau2, tau3, 1.0f);
            float tc = sqrtf(fmaf(xt, xt, 1.0f + xx));
            float dl = tc - xt;
            b4v += dl;
            g0 = fmaf(dl, nt0, g0); g1 = fmaf(dl, nt1, g1);
            g2 = fmaf(dl, nt2, g2); g3 = fmaf(dl, nt3, g3);
            g4s -= dl;
        }

        betas[tid][0] = b0v;
        betas[tid][1] = b1v;
        betas[tid][2] = b2v;
        betas[tid][3] = b3v;
        betas[tid][4] = b4v;
    }

    __syncthreads();                                 // B4: betas visible

    // ---------------- phase 2c: reconstruction (quad layout) ---------------
    if (act) {
        float b0v = betas[il2][0];
        float b1v = betas[il2][1];
        float b2v = betas[il2][2];
        float b3v = betas[il2][3];
        float b4v = betas[il2][4];

        float r[8];
        #pragma unroll
        for (int j = 0; j < 8; ++j)
            r[j] = fmaf(b0v, hv[0][j], fmaf(b1v, hv[1][j],
                   fmaf(b2v, hv[2][j], b3v * hv[3][j])));
        if (sub == 0) r[0] += b4v;

        float4* po = reinterpret_cast<float4*>(
            out + (size_t)4 * osz + (size_t)item * DD + sub * 8);
        po[0] = make_float4(r[0], r[1], r[2], r[3]);
        po[1] = make_float4(r[4], r[5], r[6], r[7]);
    }
}

extern "C" void kernel_launch(void* const* d_in, const int* in_sizes, int n_in,
                              void* d_out, int out_size, void* d_ws, size_t ws_size,
                              hipStream_t stream)
{
    const float* x0 = (const float*)d_in[0];
    const float* x1 = (const float*)d_in[1];
    const float* x2 = (const float*)d_in[2];
    const float* x3 = (const float*)d_in[3];
    const float* W0 = (const float*)d_in[4];
    const float* b0 = (const float*)d_in[5];
    const float* W1 = (const float*)d_in[6];
    const float* b1 = (const float*)d_in[7];
    const float* W2 = (const float*)d_in[8];
    const float* b2 = (const float*)d_in[9];
    const float* W3 = (const float*)d_in[10];
    const float* b3 = (const float*)d_in[11];
    const float* es = (const float*)d_in[12];
    const float* lw = (const float*)d_in[13];

    const int n_items = in_sizes[0] / SEG;   // 262144
    prep_kernel<<<9, 256, 0, stream>>>(W0, b0, W1, b1, W2, b2, W3, b3,
                                       es, (unsigned*)d_ws);

    const int gx = (n_items + IPB - 1) / IPB;       // 4096
    fused_kernel<<<gx, 256, 0, stream>>>(x0, x1, x2, x3,
                                         (const unsigned*)d_ws, lw,
                                         (float*)d_out, n_items);
}

// Round 20
// 67.249 us; speedup vs baseline: 2.3490x; 1.1621x over previous
//
#include <hip/hip_runtime.h>

#define SEG 24
#define DD  32
#define HEPS 1e-7f
#define N_ITERS 10
#define IPB 64                         // items per block

typedef _Float16 h2    __attribute__((ext_vector_type(2)));
typedef _Float16 half8 __attribute__((ext_vector_type(8)));
typedef float    f32x4 __attribute__((ext_vector_type(4)));

__device__ __forceinline__ float frcp(float x) { return __builtin_amdgcn_rcpf(x); }

__device__ __forceinline__ float qx1(float x) {
    return __int_as_float(__builtin_amdgcn_mov_dpp(__float_as_int(x), 0xB1, 0xF, 0xF, true));
}
__device__ __forceinline__ float qx2(float x) {
    return __int_as_float(__builtin_amdgcn_mov_dpp(__float_as_int(x), 0x4E, 0xF, 0xF, true));
}
__device__ __forceinline__ float qsum(float x) {
    x += qx1(x);
    x += qx2(x);
    return x;
}

__device__ __forceinline__ float acosh_coef(float a) {
    float am = fmaf(a, a, -1.0f);
    float s  = sqrtf(am);
    return __logf(a + s) * frcp(s);
}

__device__ __forceinline__ float edot8(const float a[8], const float b[8]) {
    float x = fmaf(a[0], b[0], a[1] * b[1]);
    float y = fmaf(a[2], b[2], a[3] * b[3]);
    float z = fmaf(a[4], b[4], a[5] * b[5]);
    float w = fmaf(a[6], b[6], a[7] * b[7]);
    return qsum((x + y) + (z + w));
}

// round-to-nearest-even f16 packing
__device__ __forceinline__ unsigned pk_rne_u32(float a, float b) {
    union { _Float16 h[2]; unsigned u; } c;
    c.h[0] = (_Float16)a;
    c.h[1] = (_Float16)b;
    return c.u;
}
__device__ __forceinline__ h2 pk_rne_h2(float a, float b) {
    h2 r;
    r[0] = (_Float16)a;
    r[1] = (_Float16)b;
    return r;
}

// nontemporal 16B store via clang ext-vector (HIP float4 struct is rejected)
__device__ __forceinline__ void nt_store4(float* p, float4 v) {
    f32x4 w = { v.x, v.y, v.z, v.w };
    __builtin_nontemporal_store(w, reinterpret_cast<f32x4*>(p));
}

// ws layout (dwords):
//   [0,2048)    B-fragments f16x2, ts-folded:  idx = ((s*2+nt)*64 + lane)*4 + q
//   [2048,2176) b' = b*ts  f32  (s*32 + d)
//   [2176,2180) softmax(lorentz_weights) f32
#define WS_BP_OFF 2048
#define WS_W_OFF  2176

// ============ K0: pack B fragments (W^T*ts), b*ts, softmax(lw) -> d_ws ======
__global__ __launch_bounds__(256)
void prep_kernel(const float* __restrict__ W0, const float* __restrict__ b0,
                 const float* __restrict__ W1, const float* __restrict__ b1,
                 const float* __restrict__ W2, const float* __restrict__ b2,
                 const float* __restrict__ W3, const float* __restrict__ b3,
                 const float* __restrict__ es, const float* __restrict__ lw,
                 unsigned* __restrict__ ws)
{
    const int t = blockIdx.x * blockDim.x + threadIdx.x;
    const float* Ws[4] = { W0, W1, W2, W3 };
    const float* bs[4] = { b0, b1, b2, b3 };
    const float ts = tanhf(es[0]);
    if (t < 2048) {
        int s    = t >> 9;
        int rem  = t & 511;
        int nt   = rem >> 8;
        int lane = (rem >> 2) & 63;
        int q    = rem & 3;
        int n    = nt * 16 + (lane & 15);
        int k0   = (lane >> 4) * 8 + 2 * q;
        const float* W = Ws[s];
        float a = (k0     < SEG) ? W[n * SEG + k0]     * ts : 0.0f;
        float c = (k0 + 1 < SEG) ? W[n * SEG + k0 + 1] * ts : 0.0f;
        ws[t] = pk_rne_u32(a, c);
    } else if (t < 2176) {
        int p = t - 2048;
        reinterpret_cast<float*>(ws)[WS_BP_OFF + p] = bs[p / 32][p % 32] * ts;
    } else if (t == 2176) {
        float l0 = lw[0], l1 = lw[1], l2 = lw[2], l3 = lw[3];
        float mxw = fmaxf(fmaxf(l0, l1), fmaxf(l2, l3));
        float e0 = __expf(l0 - mxw), e1 = __expf(l1 - mxw),
              e2 = __expf(l2 - mxw), e3 = __expf(l3 - mxw);
        float winv = frcp(e0 + e1 + e2 + e3);
        float* wf = reinterpret_cast<float*>(ws);
        wf[WS_W_OFF + 0] = e0 * winv;
        wf[WS_W_OFF + 1] = e1 * winv;
        wf[WS_W_OFF + 2] = e2 * winv;
        wf[WS_W_OFF + 3] = e3 * winv;
    }
}

// ============ K1: fused; MFMA encode + LDS hand-off + 5-d Frechet ===========
#define GMV(o0,o1,o2,o3,o4, v0,v1,v2,v3,v4)                                   \
    o0 = fmaf(G00,(v0), fmaf(G01,(v1), fmaf(G02,(v2), fmaf(G03,(v3), nt0*(v4))))); \
    o1 = fmaf(G01,(v0), fmaf(G11,(v1), fmaf(G12,(v2), fmaf(G13,(v3), nt1*(v4))))); \
    o2 = fmaf(G02,(v0), fmaf(G12,(v1), fmaf(G22,(v2), fmaf(G23,(v3), nt2*(v4))))); \
    o3 = fmaf(G03,(v0), fmaf(G13,(v1), fmaf(G23,(v2), fmaf(G33,(v3), nt3*(v4))))); \
    o4 = fmaf(nt0,(v0), fmaf(nt1,(v1), fmaf(nt2,(v2), fmaf(nt3,(v3), -(v4)))));

#define DOT5(a0,a1,a2,a3,a4, c0,c1,c2,c3,c4) \
    fmaf((a0),(c0), fmaf((a1),(c1), fmaf((a2),(c2), fmaf((a3),(c3), (a4)*(c4)))))

__global__ __launch_bounds__(256)
void fused_kernel(const float* __restrict__ x0, const float* __restrict__ x1,
                  const float* __restrict__ x2, const float* __restrict__ x3,
                  const unsigned* __restrict__ ws,
                  float* __restrict__ out, int n_items)
{
    __shared__ __align__(16) unsigned char smem[4 * IPB * 8 * 16];   // 32 KB
    float4* lds4 = reinterpret_cast<float4*>(smem);
    float*  ldsf = reinterpret_cast<float*>(smem);
    float (*gstate)[20] = reinterpret_cast<float (*)[20]>(smem);
    float (*betas)[5]   = reinterpret_cast<float (*)[5]>(smem + IPB * 20 * 4);

    const int tid   = threadIdx.x;
    const int item0 = blockIdx.x * IPB;
    const size_t osz = (size_t)n_items * DD;

    const float* wsf = reinterpret_cast<const float*>(ws);

    // ---------------- phase 1: MFMA encode, one stream per wave ------------
    {
        const int w    = tid >> 6;                   // wave id = stream id
        const int lane = tid & 63;
        const int g    = lane >> 4;
        const int lm   = lane & 15;

        const float* xp;
        if      (w == 0) xp = x0;
        else if (w == 1) xp = x1;
        else if (w == 2) xp = x2;
        else             xp = x3;

        union { uint4 u; half8 v; } Bf0, Bf1;
        Bf0.u = reinterpret_cast<const uint4*>(ws)[(w * 2 + 0) * 64 + lane];
        Bf1.u = reinterpret_cast<const uint4*>(ws)[(w * 2 + 1) * 64 + lane];
        const float bv0 = wsf[WS_BP_OFF + w * 32 + lm];
        const float bv1 = wsf[WS_BP_OFF + w * 32 + 16 + lm];
        const f32x4 init0 = { bv0, bv0, bv0, bv0 };
        const f32x4 init1 = { bv1, bv1, bv1, bv1 };

        f32x4 acc[4][2];
        #pragma unroll
        for (int m = 0; m < 4; ++m) {
            union { h2 h[4]; half8 v; } A;
            A.h[0] = pk_rne_h2(0.f, 0.f); A.h[1] = pk_rne_h2(0.f, 0.f);
            A.h[2] = pk_rne_h2(0.f, 0.f); A.h[3] = pk_rne_h2(0.f, 0.f);
            int item = item0 + m * 16 + lm;
            if (g < 3 && item < n_items) {
                const float4* ap = reinterpret_cast<const float4*>(
                    xp + (size_t)item * SEG + g * 8);
                float4 a0 = ap[0], a1 = ap[1];
                A.h[0] = pk_rne_h2(a0.x, a0.y);
                A.h[1] = pk_rne_h2(a0.z, a0.w);
                A.h[2] = pk_rne_h2(a1.x, a1.y);
                A.h[3] = pk_rne_h2(a1.z, a1.w);
            }
            acc[m][0] = __builtin_amdgcn_mfma_f32_16x16x32_f16(A.v, Bf0.v, init0, 0, 0, 0);
            acc[m][1] = __builtin_amdgcn_mfma_f32_16x16x32_f16(A.v, Bf1.v, init1, 0, 0, 0);
        }

        // scatter u = acc into the swizzled LDS h-layout
        #pragma unroll
        for (int r = 0; r < 4; ++r) {
            int i7   = (g * 4 + r) & 7;
            int it_b = w * IPB + g * 4 + r;          // + m*16 via m*512 floats
            int s0 = (it_b * 8 + ((lm >> 2)       ^ i7)) * 4 + (lm & 3);
            int s1 = (it_b * 8 + ((4 + (lm >> 2)) ^ i7)) * 4 + (lm & 3);
            #pragma unroll
            for (int m = 0; m < 4; ++m) {
                ldsf[s0 + m * 512] = acc[m][0][r];
                ldsf[s1 + m * 512] = acc[m][1][r];
            }
        }
    }

    // ---------------- phase 1b: per-thread nonlinear (same wave) -----------
    {
        const int s1  = tid >> 6;
        const int il1 = tid & 63;
        const int it1 = item0 + il1;

        if (it1 < n_items) {
            float u[DD];
            #pragma unroll
            for (int j = 0; j < DD / 4; ++j) {
                float4 v = lds4[(s1 * IPB + il1) * 8 + (j ^ (il1 & 7))];
                u[4*j+0] = v.x; u[4*j+1] = v.y; u[4*j+2] = v.z; u[4*j+3] = v.w;
            }

            float q0 = 0.f, q1 = 0.f, q2 = 0.f, q3 = 0.f;
            #pragma unroll
            for (int d = 0; d < DD; d += 4) {
                q0 = fmaf(u[d+0], u[d+0], q0);
                q1 = fmaf(u[d+1], u[d+1], q1);
                q2 = fmaf(u[d+2], u[d+2], q2);
                q3 = fmaf(u[d+3], u[d+3], q3);
            }
            float sq = (q0 + q1) + (q2 + q3) - 2.0f * u[0] * u[0];
            sq = fmaxf(sq, 1e-12f);
            float nrm = sqrtf(sq);
            float ep = __expf(nrm), em = frcp(ep);
            float sh = 0.5f * (ep - em);
            float sc = sh * frcp(fmaxf(nrm, HEPS));

            float r0 = 0.f, r1 = 0.f, r2 = 0.f, r3 = 0.f;
            #pragma unroll
            for (int d = 1; d < DD; ++d) {
                float yv = sc * u[d];
                u[d] = yv;
                if ((d & 3) == 0) r0 = fmaf(yv, yv, r0);
                else if ((d & 3) == 1) r1 = fmaf(yv, yv, r1);
                else if ((d & 3) == 2) r2 = fmaf(yv, yv, r2);
                else r3 = fmaf(yv, yv, r3);
            }
            u[0] = sqrtf(1.0f + (r0 + r1) + (r2 + r3));      // projx time comp

            #pragma unroll
            for (int j = 0; j < DD / 4; ++j) {
                int slot = (s1 * IPB + il1) * 8 + (j ^ (il1 & 7));
                lds4[slot] = make_float4(u[4*j+0], u[4*j+1], u[4*j+2], u[4*j+3]);
            }
        }
    }

    __syncthreads();                                 // B1: lds4 h complete

    // ---------------- phase 1.5: cooperative dense h store (nontemporal) ---
    #pragma unroll
    for (int c = 0; c < 8; ++c) {
        int f   = c * 256 + tid;
        int s   = f >> 9;
        int rem = f & 511;
        int it  = rem >> 3;
        int j   = rem & 7;
        if (item0 + it < n_items) {
            int slot = (s * IPB + it) * 8 + (j ^ (it & 7));
            nt_store4(out + (size_t)s * osz + (size_t)item0 * DD + (size_t)rem * 4,
                      lds4[slot]);
        }
    }

    // ---------------- phase 2a: quad-layout hv load + Gram (to registers) --
    const int il2  = tid >> 2;
    const int sub  = tid & 3;
    const int item = item0 + il2;
    const bool act = (item < n_items);

    float hv[4][8];
    float Ga1=0,Ga2=0,Ga3=0, Gb1=0,Gb2=0, Gc0=0;
    float tau0r=0, tau1r=0, tau2r=0, tau3r=0;

    if (act) {
        #pragma unroll
        for (int s = 0; s < 4; ++s) {
            float4 a = lds4[(s * IPB + il2) * 8 + ((2*sub)     ^ (il2 & 7))];
            float4 b = lds4[(s * IPB + il2) * 8 + ((2*sub + 1) ^ (il2 & 7))];
            hv[s][0] = a.x; hv[s][1] = a.y; hv[s][2] = a.z; hv[s][3] = a.w;
            hv[s][4] = b.x; hv[s][5] = b.y; hv[s][6] = b.z; hv[s][7] = b.w;
        }

        const float is0 = (sub == 0) ? 1.0f : 0.0f;
        tau0r = qsum(is0 * hv[0][0]);
        tau1r = qsum(is0 * hv[1][0]);
        tau2r = qsum(is0 * hv[2][0]);
        tau3r = qsum(is0 * hv[3][0]);

        float d01 = edot8(hv[0], hv[1]);
        float d02 = edot8(hv[0], hv[2]);
        float d03 = edot8(hv[0], hv[3]);
        float d12 = edot8(hv[1], hv[2]);
        float d13 = edot8(hv[1], hv[3]);
        float d23 = edot8(hv[2], hv[3]);

        Ga1 = fmaf(-2.0f*tau0r, tau1r, d01);
        Ga2 = fmaf(-2.0f*tau0r, tau2r, d02);
        Ga3 = fmaf(-2.0f*tau0r, tau3r, d03);
        Gb1 = fmaf(-2.0f*tau1r, tau2r, d12);
        Gb2 = fmaf(-2.0f*tau1r, tau3r, d13);
        Gc0 = fmaf(-2.0f*tau2r, tau3r, d23);
    }

    __syncthreads();                // B2: all lds4 reads done -> safe to alias

    if (act && sub == 0) {
        float4* g4 = reinterpret_cast<float4*>(gstate[il2]);
        g4[0] = make_float4(Ga1, Ga2, Ga3, Gb1);
        g4[1] = make_float4(Gb2, Gc0, tau0r, tau1r);
        g4[2] = make_float4(tau2r, tau3r, 0.0f, 0.0f);
    }

    __syncthreads();                                 // B3: gstate visible

    // ---------------- phase 2b: 5-d Frechet, ONE lane per item -------------
    if (tid < IPB && (item0 + tid) < n_items) {
        const float w0 = wsf[WS_W_OFF + 0];          // wave-uniform s_loads
        const float w1 = wsf[WS_W_OFF + 1];
        const float w2 = wsf[WS_W_OFF + 2];
        const float w3 = wsf[WS_W_OFF + 3];

        const float4* g4 = reinterpret_cast<const float4*>(gstate[tid]);
        float4 ga = g4[0], gb = g4[1], gc = g4[2];
        const float G00 = -1.0f, G11 = -1.0f, G22 = -1.0f, G33 = -1.0f;
        float G01 = ga.x, G02 = ga.y, G03 = ga.z, G12 = ga.w;
        float G13 = gb.x, G23 = gb.y;
        float tau0 = gb.z, tau1 = gb.w, tau2 = gc.x, tau3 = gc.y;
        float nt0 = -tau0, nt1 = -tau1, nt2 = -tau2, nt3 = -tau3;

        float b0v, b1v, b2v, b3v, b4v, g0, g1, g2, g3, g4s;
        {
            float al0 = fmaxf(tau0, 1.0f + HEPS);
            float al1 = fmaxf(tau1, 1.0f + HEPS);
            float al2 = fmaxf(tau2, 1.0f + HEPS);
            float al3 = fmaxf(tau3, 1.0f + HEPS);
            float cc0 = w0 * acosh_coef(al0);
            float cc1 = w1 * acosh_coef(al1);
            float cc2 = w2 * acosh_coef(al2);
            float cc3 = w3 * acosh_coef(al3);
            b0v = cc0; b1v = cc1; b2v = cc2; b3v = cc3;
            b4v = -DOT5(cc0, cc1, cc2, cc3, 0.0f, al0, al1, al2, al3, 0.0f);

            GMV(g0, g1, g2, g3, g4s, b0v, b1v, b2v, b3v, b4v);
            float gq = DOT5(g0, g1, g2, g3, g4s, b0v, b1v, b2v, b3v, b4v);
            float sq = fmaxf(gq, 1e-12f);
            float nrm = sqrtf(sq);
            float ep = __expf(nrm), em = frcp(ep);
            float ch = 0.5f * (ep + em);
            float sc = 0.5f * (ep - em) * frcp(fmaxf(nrm, HEPS));
            b0v *= sc; b1v *= sc; b2v *= sc; b3v *= sc;
            b4v = fmaf(sc, b4v, ch);

            GMV(g0, g1, g2, g3, g4s, b0v, b1v, b2v, b3v, b4v);
            float xx = DOT5(g0, g1, g2, g3, g4s, b0v, b1v, b2v, b3v, b4v);
            float xt = DOT5(b0v, b1v, b2v, b3v, b4v, tau0, tau1, tau2, tau3, 1.0f);
            float tc = sqrtf(fmaf(xt, xt, 1.0f + xx));
            float dl = tc - xt;
            b4v += dl;
            g0 = fmaf(dl, nt0, g0); g1 = fmaf(dl, nt1, g1);
            g2 = fmaf(dl, nt2, g2); g3 = fmaf(dl, nt3, g3);
            g4s -= dl;
        }

        for (int it = 0; it < N_ITERS; ++it) {
            float al0 = fmaxf(-g0, 1.0f + HEPS);
            float al1 = fmaxf(-g1, 1.0f + HEPS);
            float al2 = fmaxf(-g2, 1.0f + HEPS);
            float al3 = fmaxf(-g3, 1.0f + HEPS);
            float cc0 = w0 * acosh_coef(al0);
            float cc1 = w1 * acosh_coef(al1);
            float cc2 = w2 * acosh_coef(al2);
            float cc3 = w3 * acosh_coef(al3);
            float S = DOT5(cc0, cc1, cc2, cc3, 0.0f, al0, al1, al2, al3, 0.0f);

            float gm0 = fmaf(-S, b0v, cc0);
            float gm1 = fmaf(-S, b1v, cc1);
            float gm2 = fmaf(-S, b2v, cc2);
            float gm3 = fmaf(-S, b3v, cc3);
            float gm4 = -S * b4v;

            float Gg0, Gg1, Gg2, Gg3, Gg4;
            GMV(Gg0, Gg1, Gg2, Gg3, Gg4, gm0, gm1, gm2, gm3, gm4);
            float qq = DOT5(Gg0, Gg1, Gg2, Gg3, Gg4, gm0, gm1, gm2, gm3, gm4);

            float sq = fmaxf(0.25f * qq, 1e-12f);
            float nrm = sqrtf(sq);
            float ep = __expf(nrm), em = frcp(ep);
            float ch = 0.5f * (ep + em);
            float sc = 0.25f * (ep - em) * frcp(fmaxf(nrm, HEPS));

            b0v = fmaf(ch, b0v, sc * gm0);
            b1v = fmaf(ch, b1v, sc * gm1);
            b2v = fmaf(ch, b2v, sc * gm2);
            b3v = fmaf(ch, b3v, sc * gm3);
            b4v = fmaf(ch, b4v, sc * gm4);
            g0  = fmaf(ch, g0, sc * Gg0);
            g1  = fmaf(ch, g1, sc * Gg1);
            g2  = fmaf(ch, g2, sc * Gg2);
            g3  = fmaf(ch, g3, sc * Gg3);
            g4s = fmaf(ch, g4s, sc * Gg4);

            float xx = DOT5(g0, g1, g2, g3, g4s, b0v, b1v, b2v, b3v, b4v);
            float xt = DOT5(b0v, b1v, b2v, b3v, b4v, tau0, tau1, tau2, tau3, 1.0f);
            float tc = sqrtf(fmaf(xt, xt, 1.0f + xx));
            float dl = tc - xt;
            b4v += dl;
            g0 = fmaf(dl, nt0, g0); g1 = fmaf(dl, nt1, g1);
            g2 = fmaf(dl, nt2, g2); g3 = fmaf(dl, nt3, g3);
            g4s -= dl;
        }

        betas[tid][0] = b0v;
        betas[tid][1] = b1v;
        betas[tid][2] = b2v;
        betas[tid][3] = b3v;
        betas[tid][4] = b4v;
    }

    __syncthreads();                                 // B4: betas visible

    // ---------------- phase 2c: reconstruction (quad layout, nontemporal) --
    if (act) {
        float b0v = betas[il2][0];
        float b1v = betas[il2][1];
        float b2v = betas[il2][2];
        float b3v = betas[il2][3];
        float b4v = betas[il2][4];

        float r[8];
        #pragma unroll
        for (int j = 0; j < 8; ++j)
            r[j] = fmaf(b0v, hv[0][j], fmaf(b1v, hv[1][j],
                   fmaf(b2v, hv[2][j], b3v * hv[3][j])));
        if (sub == 0) r[0] += b4v;

        float* po = out + (size_t)4 * osz + (size_t)item * DD + sub * 8;
        nt_store4(po + 0, make_float4(r[0], r[1], r[2], r[3]));
        nt_store4(po + 4, make_float4(r[4], r[5], r[6], r[7]));
    }
}

extern "C" void kernel_launch(void* const* d_in, const int* in_sizes, int n_in,
                              void* d_out, int out_size, void* d_ws, size_t ws_size,
                              hipStream_t stream)
{
    const float* x0 = (const float*)d_in[0];
    const float* x1 = (const float*)d_in[1];
    const float* x2 = (const float*)d_in[2];
    const float* x3 = (const float*)d_in[3];
    const float* W0 = (const float*)d_in[4];
    const float* b0 = (const float*)d_in[5];
    const float* W1 = (const float*)d_in[6];
    const float* b1 = (const float*)d_in[7];
    const float* W2 = (const float*)d_in[8];
    const float* b2 = (const float*)d_in[9];
    const float* W3 = (const float*)d_in[10];
    const float* b3 = (const float*)d_in[11];
    const float* es = (const float*)d_in[12];
    const float* lw = (const float*)d_in[13];

    const int n_items = in_sizes[0] / SEG;   // 262144
    prep_kernel<<<9, 256, 0, stream>>>(W0, b0, W1, b1, W2, b2, W3, b3,
                                       es, lw, (unsigned*)d_ws);

    const int gx = (n_items + IPB - 1) / IPB;       // 4096
    fused_kernel<<<gx, 256, 0, stream>>>(x0, x1, x2, x3,
                                         (const unsigned*)d_ws,
                                         (float*)d_out, n_items);
}